// Round 2
// baseline (217.160 us; speedup 1.0000x reference)
//
#include <hip/hip_runtime.h>
#include <hip/hip_bf16.h>

// Problem constants: B=4, L=2048, H=8, D=64, SAMPLE_K=N_TOP=40
#define BB 4
#define LL 2048
#define HH 8
#define DD 64
#define SK 40
#define NT 40
#define CH 256              // keys per attn chunk
#define NCH (LL / CH)       // 8 chunks per (b,h)
#define QH 20               // queries per attn block (40 split in 2)

#define WS 10               // samples per wave (4 waves x 10 = 40)

// ---------------------------------------------------------------------------
// Kernel 1: M[bh][l] = max_s(q . k_{idx[l,s]}) - (sum_s q . k_{idx[l,s]}) / L
//
// Round 14/15: the old LDS staging pipeline was an IDENTITY transpose — the
// consume layout (s_lo*512 + h*64 + q*16 with h=(lane>>2)&7, q=lane&3) equals
// lane*16, the rows' native contiguous layout. Each lane loads its 64B K
// fragment DIRECTLY from global (4x float4 on one 64B line; a half-wave
// covers a full 2KB row contiguously). All 5 sample-pairs fully unrolled:
// 5 idx loads, then 20 float4 K loads all in flight -> latency hidden by ILP,
// no LDS buffer (35KB -> 64B), no barriers/lgkmcnt in the hot path.
// Arrays are constant-indexed after full unroll -> stay in VGPRs.
// ---------------------------------------------------------------------------
__global__ __launch_bounds__(256, 4) void compute_m_kernel(
        const float* __restrict__ Q, const float* __restrict__ K,
        const int* __restrict__ idx, float* __restrict__ M) {
    __shared__ float2 mlpart[4][HH];

    int blk = blockIdx.x;
    int x = blk & 7, g = blk >> 3;
    int b = x >> 1;                    // XCD pair -> batch (L2 locality)
    int l = (g << 1) | (x & 1);
    int t = threadIdx.x;
    int lane = t & 63, w = t >> 6;
    int s_lo = lane >> 5;              // which sample of the pair
    int h    = (lane >> 2) & 7;        // head
    int q    = lane & 3;               // 16-dim quarter

    const float4* Qb = (const float4*)(Q + ((size_t)b * LL + l) * 512 + h * 64 + q * 16);
    float4 qf0 = Qb[0], qf1 = Qb[1], qf2 = Qb[2], qf3 = Qb[3];

    // lane's fragment offset within a row-pair: (lane&31)*16 floats = 64B
    const float* Kb = K + (size_t)b * LL * 512 + (lane & 31) * 16;
    const int* ib = idx + (size_t)l * SK + w * WS + s_lo;

    // all 5 idx loads issued together (uniform addr within each half-wave ->
    // broadcast); then all 20 K float4 loads in flight at once
    int ks[5];
    #pragma unroll
    for (int p = 0; p < 5; ++p) ks[p] = ib[2 * p];

    float4 kd[5][4];
    #pragma unroll
    for (int p = 0; p < 5; ++p) {
        const float4* src = (const float4*)(Kb + (size_t)ks[p] * 512);
        kd[p][0] = src[0];
        kd[p][1] = src[1];
        kd[p][2] = src[2];
        kd[p][3] = src[3];
    }

    float mx = -INFINITY, sm = 0.0f;
    #pragma unroll
    for (int p = 0; p < 5; ++p) {
        float pd = qf0.x*kd[p][0].x + qf0.y*kd[p][0].y
                 + qf0.z*kd[p][0].z + qf0.w*kd[p][0].w
                 + qf1.x*kd[p][1].x + qf1.y*kd[p][1].y
                 + qf1.z*kd[p][1].z + qf1.w*kd[p][1].w
                 + qf2.x*kd[p][2].x + qf2.y*kd[p][2].y
                 + qf2.z*kd[p][2].z + qf2.w*kd[p][2].w
                 + qf3.x*kd[p][3].x + qf3.y*kd[p][3].y
                 + qf3.z*kd[p][3].z + qf3.w*kd[p][3].w;
        pd += __shfl_xor(pd, 1, 64);
        pd += __shfl_xor(pd, 2, 64);
        mx = fmaxf(mx, pd);
        sm += pd;
    }

    // merge the two pair-halves (lane ^ 32 holds the other sample's stats)
    mx = fmaxf(mx, __shfl_xor(mx, 32, 64));
    sm += __shfl_xor(sm, 32, 64);

    if ((lane & 0x23) == 0)            // q==0 && s_lo==0 -> lane = h*4
        mlpart[w][h] = make_float2(mx, sm);
    __syncthreads();

    if (t < HH) {
        float MX = -INFINITY, SM = 0.0f;
        #pragma unroll
        for (int w2 = 0; w2 < 4; ++w2) {
            float2 ml = mlpart[w2][t];
            MX = fmaxf(MX, ml.x);
            SM += ml.y;
        }
        M[((size_t)b * HH + t) * LL + l] = MX - SM * (1.0f / (float)LL);
    }
}

// ---------------------------------------------------------------------------
// Kernel 2: top-40 per (b,h), lower index wins ties. Incremental argmax.
// ---------------------------------------------------------------------------
__global__ __launch_bounds__(256) void topk_kernel(const float* __restrict__ M,
                                                   int* __restrict__ topi) {
    __shared__ unsigned long long keys[LL];   // 16 KB
    __shared__ unsigned long long wmax[4];
    __shared__ int win;
    int bh = blockIdx.x;
    int t  = threadIdx.x;
    int lane = t & 63, w = t >> 6;

    unsigned long long kmax = 0ULL;
    #pragma unroll
    for (int j = 0; j < 8; ++j) {
        int i = t + 256 * j;
        unsigned int bits = __float_as_uint(M[(size_t)bh * LL + i]);
        bits = (bits & 0x80000000u) ? ~bits : (bits | 0x80000000u);
        unsigned long long k = ((unsigned long long)bits << 11)
                             | (unsigned int)(LL - 1 - i);
        keys[i] = k;
        if (k > kmax) kmax = k;
    }
    __syncthreads();

    for (int u = 0; u < NT; ++u) {
        unsigned long long k = kmax;
        #pragma unroll
        for (int off = 32; off >= 1; off >>= 1) {
            unsigned long long o = __shfl_xor(k, off, 64);
            if (o > k) k = o;
        }
        if (lane == 0) wmax[w] = k;
        __syncthreads();
        if (t == 0) {
            unsigned long long k0 = wmax[0];
            if (wmax[1] > k0) k0 = wmax[1];
            if (wmax[2] > k0) k0 = wmax[2];
            if (wmax[3] > k0) k0 = wmax[3];
            int i = (LL - 1) - (int)(k0 & 0x7FF);
            topi[bh * NT + u] = i;
            keys[i] = 0ULL;
            win = i;
        }
        __syncthreads();
        if ((win & 255) == t) {          // only the owner rescans
            kmax = 0ULL;
            #pragma unroll
            for (int j = 0; j < 8; ++j) {
                unsigned long long kk = keys[t + 256 * j];
                if (kk > kmax) kmax = kk;
            }
        }
    }
}

// ---------------------------------------------------------------------------
// Kernel 3: flash-chunked attention, query-split.
// __launch_bounds__(256,3) keeps kreg/vcol in registers (round 7 spill fix).
// (m,l) packed float2 store (round 8 granule-waste fix).
// ---------------------------------------------------------------------------
__global__ __launch_bounds__(256, 3) void attn_kernel(
        const float* __restrict__ Q, const float* __restrict__ K,
        const float* __restrict__ V, const int* __restrict__ topi,
        float2* __restrict__ pml, float* __restrict__ po) {
    __shared__ float  qs[QH][DD];        //  5120 B
    __shared__ float4 e4buf[4][64];      //  4096 B
    __shared__ float  oarea[4][QH][DD];  // 20480 B
    __shared__ float  mlarea[4][QH][2];  //   640 B

    int blk = blockIdx.x;
    int qh  = blk >> 8;                  // 0/1 query half
    int cc2 = blk & 255;
    int c   = cc2 & (NCH - 1);
    int bh  = cc2 >> 3;
    int h = bh & (HH - 1), b = bh >> 3;
    int t = threadIdx.x, lane = t & 63, w = t >> 6;
    int u0 = qh * QH;

    for (int i = t; i < QH * DD; i += 256) {
        int u = i >> 6, d = i & 63;
        int lq = topi[bh * NT + u0 + u];
        qs[u][d] = Q[(((size_t)b * LL + lq) * HH + h) * DD + d];
    }

    int key = c * CH + w * 64 + lane;
    const float4* kr = (const float4*)&K[(((size_t)b * LL + key) * HH + h) * DD];
    float4 kreg[16];
    #pragma unroll
    for (int j = 0; j < 16; ++j) kreg[j] = kr[j];

    float vcol[64];
    const float* vb = &V[(((size_t)b * LL + c * CH + w * 64) * HH + h) * DD + lane];
    #pragma unroll
    for (int j = 0; j < 64; ++j) vcol[j] = vb[(size_t)j * HH * DD];

    __syncthreads();   // qs ready

    for (int uq = 0; uq < QH / 4; ++uq) {
        float o0 = 0, o1 = 0, o2 = 0, o3 = 0;
        float mv0, mv1, mv2, mv3, lv0, lv1, lv2, lv3;
        float4 ev;
        #pragma unroll
        for (int j = 0; j < 4; ++j) {
            int u = uq * 4 + j;
            const float4* q4 = (const float4*)&qs[u][0];
            float s = 0.0f;
            #pragma unroll
            for (int cc = 0; cc < 16; ++cc) {
                float4 qv = q4[cc];
                s += qv.x * kreg[cc].x + qv.y * kreg[cc].y
                   + qv.z * kreg[cc].z + qv.w * kreg[cc].w;
            }
            s *= 0.125f;   // 1/sqrt(64)
            float m = s;
            #pragma unroll
            for (int off = 32; off >= 1; off >>= 1)
                m = fmaxf(m, __shfl_xor(m, off, 64));
            float e = __expf(s - m);
            float ls = e;
            #pragma unroll
            for (int off = 32; off >= 1; off >>= 1)
                ls += __shfl_xor(ls, off, 64);
            if (j == 0) { mv0 = m; lv0 = ls; ev.x = e; }
            if (j == 1) { mv1 = m; lv1 = ls; ev.y = e; }
            if (j == 2) { mv2 = m; lv2 = ls; ev.z = e; }
            if (j == 3) { mv3 = m; lv3 = ls; ev.w = e; }
        }
        e4buf[w][lane] = ev;
        asm volatile("s_waitcnt lgkmcnt(0)" ::: "memory");
        #pragma unroll
        for (int l2 = 0; l2 < 64; ++l2) {      // FULL unroll: vcol static
            float4 e = e4buf[w][l2];
            float  v = vcol[l2];
            o0 += e.x * v; o1 += e.y * v; o2 += e.z * v; o3 += e.w * v;
        }
        oarea[w][uq * 4 + 0][lane] = o0;
        oarea[w][uq * 4 + 1][lane] = o1;
        oarea[w][uq * 4 + 2][lane] = o2;
        oarea[w][uq * 4 + 3][lane] = o3;
        if (lane == 0) {
            mlarea[w][uq * 4 + 0][0] = mv0; mlarea[w][uq * 4 + 0][1] = lv0;
            mlarea[w][uq * 4 + 1][0] = mv1; mlarea[w][uq * 4 + 1][1] = lv1;
            mlarea[w][uq * 4 + 2][0] = mv2; mlarea[w][uq * 4 + 2][1] = lv2;
            mlarea[w][uq * 4 + 3][0] = mv3; mlarea[w][uq * 4 + 3][1] = lv3;
        }
    }
    __syncthreads();

    for (int i = t; i < QH * DD; i += 256) {
        int u = i >> 6, d = i & 63;
        float m0 = mlarea[0][u][0], m1 = mlarea[1][u][0];
        float m2 = mlarea[2][u][0], m3 = mlarea[3][u][0];
        float mb = fmaxf(fmaxf(m0, m1), fmaxf(m2, m3));
        float s0 = __expf(m0 - mb), s1 = __expf(m1 - mb);
        float s2 = __expf(m2 - mb), s3 = __expf(m3 - mb);
        float ob = oarea[0][u][d] * s0 + oarea[1][u][d] * s1
                 + oarea[2][u][d] * s2 + oarea[3][u][d] * s3;
        int gu = u0 + u;
        po[((size_t)(bh * NT + gu) * NCH + c) * DD + d] = ob;
        if (d == 0) {
            float lb = mlarea[0][u][1] * s0 + mlarea[1][u][1] * s1
                     + mlarea[2][u][1] * s2 + mlarea[3][u][1] * s3;
            pml[(bh * NT + gu) * NCH + c] = make_float2(mb, lb);
        }
    }
}

// ---------------------------------------------------------------------------
// Kernel 4: merge chunk partials. One wave per (bh,u), lane = d.
// ---------------------------------------------------------------------------
__global__ __launch_bounds__(256) void merge_kernel(
        const float2* __restrict__ pml, const float* __restrict__ po,
        float* __restrict__ out) {
    int wid  = blockIdx.x * 4 + (threadIdx.x >> 6);
    int lane = threadIdx.x & 63;
    int u  = wid % NT;
    int bh = wid / NT;
    int h = bh & (HH - 1), b = bh >> 3;
    int base = (bh * NT + u) * NCH;

    float m = -INFINITY;
    #pragma unroll
    for (int cc = 0; cc < NCH; ++cc) m = fmaxf(m, pml[base + cc].x);
    float lsum = 0.0f, o = 0.0f;
    #pragma unroll
    for (int cc = 0; cc < NCH; ++cc) {
        float2 ml = pml[base + cc];
        float sc = __expf(ml.x - m);
        lsum += ml.y * sc;
        o    += po[(size_t)(base + cc) * DD + lane] * sc;
    }
    out[(((size_t)b * NT + u) * HH + h) * DD + lane] = o / lsum;
}

extern "C" void kernel_launch(void* const* d_in, const int* in_sizes, int n_in,
                              void* d_out, int out_size, void* d_ws, size_t ws_size,
                              hipStream_t stream) {
    const float* Q   = (const float*)d_in[0];
    const float* K   = (const float*)d_in[1];
    const float* V   = (const float*)d_in[2];
    const int*   idx = (const int*)d_in[3];
    float* out = (float*)d_out;

    char* ws = (char*)d_ws;
    float*  M    = (float*)ws;                        ws += (size_t)BB * HH * LL * sizeof(float);
    int*    topi = (int*)ws;                          ws += (size_t)BB * HH * NT * sizeof(int);
    float2* pml  = (float2*)ws;                       ws += (size_t)BB * HH * NT * NCH * sizeof(float2);
    float*  po   = (float*)ws;                        // 2.62 MB

    hipLaunchKernelGGL(compute_m_kernel, dim3(BB * LL), dim3(256), 0, stream,
                       Q, K, idx, M);
    hipLaunchKernelGGL(topk_kernel, dim3(BB * HH), dim3(256), 0, stream, M, topi);
    hipLaunchKernelGGL(attn_kernel, dim3(2 * BB * HH * NCH), dim3(256), 0, stream,
                       Q, K, V, topi, pml, po);
    hipLaunchKernelGGL(merge_kernel, dim3(BB * HH * NT / 4), dim3(256), 0, stream,
                       pml, po, out);
}

// Round 3
// 182.691 us; speedup vs baseline: 1.1887x; 1.1887x over previous
//
#include <hip/hip_runtime.h>
#include <hip/hip_bf16.h>

// Problem constants: B=4, L=2048, H=8, D=64, SAMPLE_K=N_TOP=40
#define BB 4
#define LL 2048
#define HH 8
#define DD 64
#define SK 40
#define NT 40
#define CH 256              // keys per attn chunk
#define NCH (LL / CH)       // 8 chunks per (b,h)
#define QH 20               // queries per attn block (40 split in 2)

#define WS 10               // samples per wave (4 waves x 10 = 40)

// ---------------------------------------------------------------------------
// Kernel 1: M[bh][l] = max_s(q . k_{idx[l,s]}) - (sum_s q . k_{idx[l,s]}) / L
//
// Round 15 post-mortem: letting the compiler schedule the 20 direct K loads
// failed — VGPR_Count=36 showed LLVM sank every load to its use (2 loads in
// flight, latency-serial, 92us). Round 16: same direct-load structure (the
// LDS stage was an identity transpose — consume layout == native row layout,
// each lane's fragment is 64B contiguous at Krow+(lane&31)*64B), but with
// __builtin_amdgcn_sched_barrier(0) between the load block and the compute
// block: the scheduler cannot move instructions across it, so all 20
// global_load_dwordx4 issue before the first FMA -> 20-deep MLP per wave.
// ---------------------------------------------------------------------------
__global__ __launch_bounds__(256, 4) void compute_m_kernel(
        const float* __restrict__ Q, const float* __restrict__ K,
        const int* __restrict__ idx, float* __restrict__ M) {
    __shared__ float2 mlpart[4][HH];

    int blk = blockIdx.x;
    int x = blk & 7, g = blk >> 3;
    int b = x >> 1;                    // XCD pair -> batch (L2 locality)
    int l = (g << 1) | (x & 1);
    int t = threadIdx.x;
    int lane = t & 63, w = t >> 6;
    int s_lo = lane >> 5;              // which sample of the pair
    int h    = (lane >> 2) & 7;        // head
    int q    = lane & 3;               // 16-dim quarter

    const float4* Qb = (const float4*)(Q + ((size_t)b * LL + l) * 512 + h * 64 + q * 16);
    float4 qf0 = Qb[0], qf1 = Qb[1], qf2 = Qb[2], qf3 = Qb[3];

    // lane's fragment offset within a row-pair: (lane&31)*16 floats = 64B
    const float* Kb = K + (size_t)b * LL * 512 + (lane & 31) * 16;
    const int* ib = idx + (size_t)l * SK + w * WS + s_lo;

    // 5 idx loads (uniform within each half-wave -> broadcast), then all 20
    // K float4 loads issued back-to-back.
    int ks[5];
    #pragma unroll
    for (int p = 0; p < 5; ++p) ks[p] = ib[2 * p];

    float4 kd[5][4];
    #pragma unroll
    for (int p = 0; p < 5; ++p) {
        const float4* src = (const float4*)(Kb + (size_t)ks[p] * 512);
        kd[p][0] = src[0];
        kd[p][1] = src[1];
        kd[p][2] = src[2];
        kd[p][3] = src[3];
    }

    // Hard scheduling fence: nothing may cross. All 20 loads stay issued
    // above; the FMA chain below consumes them as they land (compiler emits
    // decreasing vmcnt waits). This is what the LDS pipeline used to force.
    __builtin_amdgcn_sched_barrier(0);

    float mx = -INFINITY, sm = 0.0f;
    #pragma unroll
    for (int p = 0; p < 5; ++p) {
        float pd = qf0.x*kd[p][0].x + qf0.y*kd[p][0].y
                 + qf0.z*kd[p][0].z + qf0.w*kd[p][0].w
                 + qf1.x*kd[p][1].x + qf1.y*kd[p][1].y
                 + qf1.z*kd[p][1].z + qf1.w*kd[p][1].w
                 + qf2.x*kd[p][2].x + qf2.y*kd[p][2].y
                 + qf2.z*kd[p][2].z + qf2.w*kd[p][2].w
                 + qf3.x*kd[p][3].x + qf3.y*kd[p][3].y
                 + qf3.z*kd[p][3].z + qf3.w*kd[p][3].w;
        pd += __shfl_xor(pd, 1, 64);
        pd += __shfl_xor(pd, 2, 64);
        mx = fmaxf(mx, pd);
        sm += pd;
    }

    // merge the two pair-halves (lane ^ 32 holds the other sample's stats)
    mx = fmaxf(mx, __shfl_xor(mx, 32, 64));
    sm += __shfl_xor(sm, 32, 64);

    if ((lane & 0x23) == 0)            // q==0 && s_lo==0 -> lane = h*4
        mlpart[w][h] = make_float2(mx, sm);
    __syncthreads();

    if (t < HH) {
        float MX = -INFINITY, SM = 0.0f;
        #pragma unroll
        for (int w2 = 0; w2 < 4; ++w2) {
            float2 ml = mlpart[w2][t];
            MX = fmaxf(MX, ml.x);
            SM += ml.y;
        }
        M[((size_t)b * HH + t) * LL + l] = MX - SM * (1.0f / (float)LL);
    }
}

// ---------------------------------------------------------------------------
// Kernel 2: top-40 per (b,h), lower index wins ties. Incremental argmax.
// ---------------------------------------------------------------------------
__global__ __launch_bounds__(256) void topk_kernel(const float* __restrict__ M,
                                                   int* __restrict__ topi) {
    __shared__ unsigned long long keys[LL];   // 16 KB
    __shared__ unsigned long long wmax[4];
    __shared__ int win;
    int bh = blockIdx.x;
    int t  = threadIdx.x;
    int lane = t & 63, w = t >> 6;

    unsigned long long kmax = 0ULL;
    #pragma unroll
    for (int j = 0; j < 8; ++j) {
        int i = t + 256 * j;
        unsigned int bits = __float_as_uint(M[(size_t)bh * LL + i]);
        bits = (bits & 0x80000000u) ? ~bits : (bits | 0x80000000u);
        unsigned long long k = ((unsigned long long)bits << 11)
                             | (unsigned int)(LL - 1 - i);
        keys[i] = k;
        if (k > kmax) kmax = k;
    }
    __syncthreads();

    for (int u = 0; u < NT; ++u) {
        unsigned long long k = kmax;
        #pragma unroll
        for (int off = 32; off >= 1; off >>= 1) {
            unsigned long long o = __shfl_xor(k, off, 64);
            if (o > k) k = o;
        }
        if (lane == 0) wmax[w] = k;
        __syncthreads();
        if (t == 0) {
            unsigned long long k0 = wmax[0];
            if (wmax[1] > k0) k0 = wmax[1];
            if (wmax[2] > k0) k0 = wmax[2];
            if (wmax[3] > k0) k0 = wmax[3];
            int i = (LL - 1) - (int)(k0 & 0x7FF);
            topi[bh * NT + u] = i;
            keys[i] = 0ULL;
            win = i;
        }
        __syncthreads();
        if ((win & 255) == t) {          // only the owner rescans
            kmax = 0ULL;
            #pragma unroll
            for (int j = 0; j < 8; ++j) {
                unsigned long long kk = keys[t + 256 * j];
                if (kk > kmax) kmax = kk;
            }
        }
    }
}

// ---------------------------------------------------------------------------
// Kernel 3: flash-chunked attention, query-split.
// __launch_bounds__(256,3) keeps kreg/vcol in registers (round 7 spill fix).
// (m,l) packed float2 store (round 8 granule-waste fix).
// ---------------------------------------------------------------------------
__global__ __launch_bounds__(256, 3) void attn_kernel(
        const float* __restrict__ Q, const float* __restrict__ K,
        const float* __restrict__ V, const int* __restrict__ topi,
        float2* __restrict__ pml, float* __restrict__ po) {
    __shared__ float  qs[QH][DD];        //  5120 B
    __shared__ float4 e4buf[4][64];      //  4096 B
    __shared__ float  oarea[4][QH][DD];  // 20480 B
    __shared__ float  mlarea[4][QH][2];  //   640 B

    int blk = blockIdx.x;
    int qh  = blk >> 8;                  // 0/1 query half
    int cc2 = blk & 255;
    int c   = cc2 & (NCH - 1);
    int bh  = cc2 >> 3;
    int h = bh & (HH - 1), b = bh >> 3;
    int t = threadIdx.x, lane = t & 63, w = t >> 6;
    int u0 = qh * QH;

    for (int i = t; i < QH * DD; i += 256) {
        int u = i >> 6, d = i & 63;
        int lq = topi[bh * NT + u0 + u];
        qs[u][d] = Q[(((size_t)b * LL + lq) * HH + h) * DD + d];
    }

    int key = c * CH + w * 64 + lane;
    const float4* kr = (const float4*)&K[(((size_t)b * LL + key) * HH + h) * DD];
    float4 kreg[16];
    #pragma unroll
    for (int j = 0; j < 16; ++j) kreg[j] = kr[j];

    float vcol[64];
    const float* vb = &V[(((size_t)b * LL + c * CH + w * 64) * HH + h) * DD + lane];
    #pragma unroll
    for (int j = 0; j < 64; ++j) vcol[j] = vb[(size_t)j * HH * DD];

    __syncthreads();   // qs ready

    for (int uq = 0; uq < QH / 4; ++uq) {
        float o0 = 0, o1 = 0, o2 = 0, o3 = 0;
        float mv0, mv1, mv2, mv3, lv0, lv1, lv2, lv3;
        float4 ev;
        #pragma unroll
        for (int j = 0; j < 4; ++j) {
            int u = uq * 4 + j;
            const float4* q4 = (const float4*)&qs[u][0];
            float s = 0.0f;
            #pragma unroll
            for (int cc = 0; cc < 16; ++cc) {
                float4 qv = q4[cc];
                s += qv.x * kreg[cc].x + qv.y * kreg[cc].y
                   + qv.z * kreg[cc].z + qv.w * kreg[cc].w;
            }
            s *= 0.125f;   // 1/sqrt(64)
            float m = s;
            #pragma unroll
            for (int off = 32; off >= 1; off >>= 1)
                m = fmaxf(m, __shfl_xor(m, off, 64));
            float e = __expf(s - m);
            float ls = e;
            #pragma unroll
            for (int off = 32; off >= 1; off >>= 1)
                ls += __shfl_xor(ls, off, 64);
            if (j == 0) { mv0 = m; lv0 = ls; ev.x = e; }
            if (j == 1) { mv1 = m; lv1 = ls; ev.y = e; }
            if (j == 2) { mv2 = m; lv2 = ls; ev.z = e; }
            if (j == 3) { mv3 = m; lv3 = ls; ev.w = e; }
        }
        e4buf[w][lane] = ev;
        asm volatile("s_waitcnt lgkmcnt(0)" ::: "memory");
        #pragma unroll
        for (int l2 = 0; l2 < 64; ++l2) {      // FULL unroll: vcol static
            float4 e = e4buf[w][l2];
            float  v = vcol[l2];
            o0 += e.x * v; o1 += e.y * v; o2 += e.z * v; o3 += e.w * v;
        }
        oarea[w][uq * 4 + 0][lane] = o0;
        oarea[w][uq * 4 + 1][lane] = o1;
        oarea[w][uq * 4 + 2][lane] = o2;
        oarea[w][uq * 4 + 3][lane] = o3;
        if (lane == 0) {
            mlarea[w][uq * 4 + 0][0] = mv0; mlarea[w][uq * 4 + 0][1] = lv0;
            mlarea[w][uq * 4 + 1][0] = mv1; mlarea[w][uq * 4 + 1][1] = lv1;
            mlarea[w][uq * 4 + 2][0] = mv2; mlarea[w][uq * 4 + 2][1] = lv2;
            mlarea[w][uq * 4 + 3][0] = mv3; mlarea[w][uq * 4 + 3][1] = lv3;
        }
    }
    __syncthreads();

    for (int i = t; i < QH * DD; i += 256) {
        int u = i >> 6, d = i & 63;
        float m0 = mlarea[0][u][0], m1 = mlarea[1][u][0];
        float m2 = mlarea[2][u][0], m3 = mlarea[3][u][0];
        float mb = fmaxf(fmaxf(m0, m1), fmaxf(m2, m3));
        float s0 = __expf(m0 - mb), s1 = __expf(m1 - mb);
        float s2 = __expf(m2 - mb), s3 = __expf(m3 - mb);
        float ob = oarea[0][u][d] * s0 + oarea[1][u][d] * s1
                 + oarea[2][u][d] * s2 + oarea[3][u][d] * s3;
        int gu = u0 + u;
        po[((size_t)(bh * NT + gu) * NCH + c) * DD + d] = ob;
        if (d == 0) {
            float lb = mlarea[0][u][1] * s0 + mlarea[1][u][1] * s1
                     + mlarea[2][u][1] * s2 + mlarea[3][u][1] * s3;
            pml[(bh * NT + gu) * NCH + c] = make_float2(mb, lb);
        }
    }
}

// ---------------------------------------------------------------------------
// Kernel 4: merge chunk partials. One wave per (bh,u), lane = d.
// ---------------------------------------------------------------------------
__global__ __launch_bounds__(256) void merge_kernel(
        const float2* __restrict__ pml, const float* __restrict__ po,
        float* __restrict__ out) {
    int wid  = blockIdx.x * 4 + (threadIdx.x >> 6);
    int lane = threadIdx.x & 63;
    int u  = wid % NT;
    int bh = wid / NT;
    int h = bh & (HH - 1), b = bh >> 3;
    int base = (bh * NT + u) * NCH;

    float m = -INFINITY;
    #pragma unroll
    for (int cc = 0; cc < NCH; ++cc) m = fmaxf(m, pml[base + cc].x);
    float lsum = 0.0f, o = 0.0f;
    #pragma unroll
    for (int cc = 0; cc < NCH; ++cc) {
        float2 ml = pml[base + cc];
        float sc = __expf(ml.x - m);
        lsum += ml.y * sc;
        o    += po[(size_t)(base + cc) * DD + lane] * sc;
    }
    out[(((size_t)b * NT + u) * HH + h) * DD + lane] = o / lsum;
}

extern "C" void kernel_launch(void* const* d_in, const int* in_sizes, int n_in,
                              void* d_out, int out_size, void* d_ws, size_t ws_size,
                              hipStream_t stream) {
    const float* Q   = (const float*)d_in[0];
    const float* K   = (const float*)d_in[1];
    const float* V   = (const float*)d_in[2];
    const int*   idx = (const int*)d_in[3];
    float* out = (float*)d_out;

    char* ws = (char*)d_ws;
    float*  M    = (float*)ws;                        ws += (size_t)BB * HH * LL * sizeof(float);
    int*    topi = (int*)ws;                          ws += (size_t)BB * HH * NT * sizeof(int);
    float2* pml  = (float2*)ws;                       ws += (size_t)BB * HH * NT * NCH * sizeof(float2);
    float*  po   = (float*)ws;                        // 2.62 MB

    hipLaunchKernelGGL(compute_m_kernel, dim3(BB * LL), dim3(256), 0, stream,
                       Q, K, idx, M);
    hipLaunchKernelGGL(topk_kernel, dim3(BB * HH), dim3(256), 0, stream, M, topi);
    hipLaunchKernelGGL(attn_kernel, dim3(2 * BB * HH * NCH), dim3(256), 0, stream,
                       Q, K, V, topi, pml, po);
    hipLaunchKernelGGL(merge_kernel, dim3(BB * HH * NT / 4), dim3(256), 0, stream,
                       pml, po, out);
}

// Round 4
// 182.235 us; speedup vs baseline: 1.1916x; 1.0025x over previous
//
#include <hip/hip_runtime.h>
#include <hip/hip_bf16.h>

// Problem constants: B=4, L=2048, H=8, D=64, SAMPLE_K=N_TOP=40
#define BB 4
#define LL 2048
#define HH 8
#define DD 64
#define SK 40
#define NT 40
#define CH 256              // keys per attn chunk
#define NCH (LL / CH)       // 8 chunks per (b,h)
#define QH 20               // queries per attn block (40 split in 2)

#define WS 10               // samples per wave (4 waves x 10 = 40)

typedef float f4 __attribute__((ext_vector_type(4)));

// ---------------------------------------------------------------------------
// Kernel 1: M[bh][l] = max_s(q . k_{idx[l,s]}) - (sum_s q . k_{idx[l,s]}) / L
//
// Round 17: rounds 15/16 showed the compiler will NOT keep 20 gather loads in
// flight from C source (VGPR=36 then 52; sched_barrier didn't bind regalloc).
// This version forces the pipeline with inline asm:
//   - 20 global_load_dwordx4 issued as 5 asm volatile blocks ("=&v" outputs
//     -> 80 forced-live data VGPRs, loads cannot be sunk or reordered);
//   - consumes gated by explicit descending s_waitcnt vmcnt(16/12/8/4/0);
//     the wait-asm carries the pair's data regs as "+v" operands so the FMAs
//     have a register dependence on the wait (cannot hoist; guide rule #18);
//   - an empty keep-alive asm on the Q regs BEFORE the K loads makes the
//     compiler drain its own (tracked) loads there, so it inserts no
//     pessimistic vmcnt(0) inside the hand-built pipeline. FIFO vmcnt
//     retirement keeps the descending counts conservative-safe even if
//     stray compiler loads interleave.
// Identity-transpose insight stands: each lane's fragment is 64B contiguous
// at Krow + (lane&31)*64B; no LDS staging needed.
// __launch_bounds__(256,2): VGPR cap 256 -> zero spill risk (~120 needed);
// 2 blocks/CU x 4 waves x 20KB in flight >> Little's-law requirement.
// ---------------------------------------------------------------------------
__global__ __launch_bounds__(256, 2) void compute_m_kernel(
        const float* __restrict__ Q, const float* __restrict__ K,
        const int* __restrict__ idx, float* __restrict__ M) {
    __shared__ float2 mlpart[4][HH];

    int blk = blockIdx.x;
    int x = blk & 7, g = blk >> 3;
    int b = x >> 1;                    // XCD pair -> batch (per-batch K = 4.2MB fits XCD L2)
    int l = (g << 1) | (x & 1);
    int t = threadIdx.x;
    int lane = t & 63, w = t >> 6;
    int s_lo = lane >> 5;              // which sample of the pair
    int h    = (lane >> 2) & 7;        // head
    int q    = lane & 3;               // 16-dim quarter

    const f4* Qb = (const f4*)(Q + ((size_t)b * LL + l) * 512 + h * 64 + q * 16);
    f4 qf0 = Qb[0], qf1 = Qb[1], qf2 = Qb[2], qf3 = Qb[3];

    // lane's fragment offset within a row-pair: (lane&31)*16 floats = 64B
    const float* Kb = K + (size_t)b * LL * 512 + (lane & 31) * 16;
    const int* ib = idx + (size_t)l * SK + w * WS + s_lo;

    int ks0 = ib[0], ks1 = ib[2], ks2 = ib[4], ks3 = ib[6], ks4 = ib[8];
    const float* s0 = Kb + (size_t)ks0 * 512;
    const float* s1 = Kb + (size_t)ks1 * 512;
    const float* s2 = Kb + (size_t)ks2 * 512;
    const float* s3 = Kb + (size_t)ks3 * 512;
    const float* s4 = Kb + (size_t)ks4 * 512;

    // Drain compiler-tracked loads (Q, idx) HERE, before the asm pipeline:
    // the compiler sees these uses and emits its vmcnt now, not mid-pipeline.
    asm volatile("" : "+v"(qf0), "+v"(qf1), "+v"(qf2), "+v"(qf3));

    f4 k0a, k0b, k0c, k0d, k1a, k1b, k1c, k1d, k2a, k2b, k2c, k2d;
    f4 k3a, k3b, k3c, k3d, k4a, k4b, k4c, k4d;

    #define LOADP(KA, KB_, KC, KD, SRC)                                         \
        asm volatile("global_load_dwordx4 %0, %4, off\n"                        \
                     "global_load_dwordx4 %1, %4, off offset:16\n"              \
                     "global_load_dwordx4 %2, %4, off offset:32\n"              \
                     "global_load_dwordx4 %3, %4, off offset:48"                \
                     : "=&v"(KA), "=&v"(KB_), "=&v"(KC), "=&v"(KD)              \
                     : "v"(SRC))

    LOADP(k0a, k0b, k0c, k0d, s0);
    LOADP(k1a, k1b, k1c, k1d, s1);
    LOADP(k2a, k2b, k2c, k2d, s2);
    LOADP(k3a, k3b, k3c, k3d, s3);
    LOADP(k4a, k4b, k4c, k4d, s4);
    #undef LOADP

    float mx = -INFINITY, sm = 0.0f;

    #define CONSUME(KA, KB_, KC, KD, WAIT) do {                                 \
        asm volatile(WAIT : "+v"(KA), "+v"(KB_), "+v"(KC), "+v"(KD));           \
        float pd = qf0.x*KA.x + qf0.y*KA.y + qf0.z*KA.z + qf0.w*KA.w            \
                 + qf1.x*KB_.x + qf1.y*KB_.y + qf1.z*KB_.z + qf1.w*KB_.w        \
                 + qf2.x*KC.x + qf2.y*KC.y + qf2.z*KC.z + qf2.w*KC.w            \
                 + qf3.x*KD.x + qf3.y*KD.y + qf3.z*KD.z + qf3.w*KD.w;           \
        pd += __shfl_xor(pd, 1, 64);                                            \
        pd += __shfl_xor(pd, 2, 64);                                            \
        mx = fmaxf(mx, pd);                                                     \
        sm += pd;                                                               \
    } while (0)

    CONSUME(k0a, k0b, k0c, k0d, "s_waitcnt vmcnt(16)");
    CONSUME(k1a, k1b, k1c, k1d, "s_waitcnt vmcnt(12)");
    CONSUME(k2a, k2b, k2c, k2d, "s_waitcnt vmcnt(8)");
    CONSUME(k3a, k3b, k3c, k3d, "s_waitcnt vmcnt(4)");
    CONSUME(k4a, k4b, k4c, k4d, "s_waitcnt vmcnt(0)");
    #undef CONSUME

    // merge the two pair-halves (lane ^ 32 holds the other sample's stats)
    mx = fmaxf(mx, __shfl_xor(mx, 32, 64));
    sm += __shfl_xor(sm, 32, 64);

    if ((lane & 0x23) == 0)            // q==0 && s_lo==0 -> lane = h*4
        mlpart[w][h] = make_float2(mx, sm);
    __syncthreads();

    if (t < HH) {
        float MX = -INFINITY, SM = 0.0f;
        #pragma unroll
        for (int w2 = 0; w2 < 4; ++w2) {
            float2 ml = mlpart[w2][t];
            MX = fmaxf(MX, ml.x);
            SM += ml.y;
        }
        M[((size_t)b * HH + t) * LL + l] = MX - SM * (1.0f / (float)LL);
    }
}

// ---------------------------------------------------------------------------
// Kernel 2: top-40 per (b,h), lower index wins ties. Incremental argmax.
// ---------------------------------------------------------------------------
__global__ __launch_bounds__(256) void topk_kernel(const float* __restrict__ M,
                                                   int* __restrict__ topi) {
    __shared__ unsigned long long keys[LL];   // 16 KB
    __shared__ unsigned long long wmax[4];
    __shared__ int win;
    int bh = blockIdx.x;
    int t  = threadIdx.x;
    int lane = t & 63, w = t >> 6;

    unsigned long long kmax = 0ULL;
    #pragma unroll
    for (int j = 0; j < 8; ++j) {
        int i = t + 256 * j;
        unsigned int bits = __float_as_uint(M[(size_t)bh * LL + i]);
        bits = (bits & 0x80000000u) ? ~bits : (bits | 0x80000000u);
        unsigned long long k = ((unsigned long long)bits << 11)
                             | (unsigned int)(LL - 1 - i);
        keys[i] = k;
        if (k > kmax) kmax = k;
    }
    __syncthreads();

    for (int u = 0; u < NT; ++u) {
        unsigned long long k = kmax;
        #pragma unroll
        for (int off = 32; off >= 1; off >>= 1) {
            unsigned long long o = __shfl_xor(k, off, 64);
            if (o > k) k = o;
        }
        if (lane == 0) wmax[w] = k;
        __syncthreads();
        if (t == 0) {
            unsigned long long k0 = wmax[0];
            if (wmax[1] > k0) k0 = wmax[1];
            if (wmax[2] > k0) k0 = wmax[2];
            if (wmax[3] > k0) k0 = wmax[3];
            int i = (LL - 1) - (int)(k0 & 0x7FF);
            topi[bh * NT + u] = i;
            keys[i] = 0ULL;
            win = i;
        }
        __syncthreads();
        if ((win & 255) == t) {          // only the owner rescans
            kmax = 0ULL;
            #pragma unroll
            for (int j = 0; j < 8; ++j) {
                unsigned long long kk = keys[t + 256 * j];
                if (kk > kmax) kmax = kk;
            }
        }
    }
}

// ---------------------------------------------------------------------------
// Kernel 3: flash-chunked attention, query-split.
// __launch_bounds__(256,3) keeps kreg/vcol in registers (round 7 spill fix).
// (m,l) packed float2 store (round 8 granule-waste fix).
// ---------------------------------------------------------------------------
__global__ __launch_bounds__(256, 3) void attn_kernel(
        const float* __restrict__ Q, const float* __restrict__ K,
        const float* __restrict__ V, const int* __restrict__ topi,
        float2* __restrict__ pml, float* __restrict__ po) {
    __shared__ float  qs[QH][DD];        //  5120 B
    __shared__ float4 e4buf[4][64];      //  4096 B
    __shared__ float  oarea[4][QH][DD];  // 20480 B
    __shared__ float  mlarea[4][QH][2];  //   640 B

    int blk = blockIdx.x;
    int qh  = blk >> 8;                  // 0/1 query half
    int cc2 = blk & 255;
    int c   = cc2 & (NCH - 1);
    int bh  = cc2 >> 3;
    int h = bh & (HH - 1), b = bh >> 3;
    int t = threadIdx.x, lane = t & 63, w = t >> 6;
    int u0 = qh * QH;

    for (int i = t; i < QH * DD; i += 256) {
        int u = i >> 6, d = i & 63;
        int lq = topi[bh * NT + u0 + u];
        qs[u][d] = Q[(((size_t)b * LL + lq) * HH + h) * DD + d];
    }

    int key = c * CH + w * 64 + lane;
    const float4* kr = (const float4*)&K[(((size_t)b * LL + key) * HH + h) * DD];
    float4 kreg[16];
    #pragma unroll
    for (int j = 0; j < 16; ++j) kreg[j] = kr[j];

    float vcol[64];
    const float* vb = &V[(((size_t)b * LL + c * CH + w * 64) * HH + h) * DD + lane];
    #pragma unroll
    for (int j = 0; j < 64; ++j) vcol[j] = vb[(size_t)j * HH * DD];

    __syncthreads();   // qs ready

    for (int uq = 0; uq < QH / 4; ++uq) {
        float o0 = 0, o1 = 0, o2 = 0, o3 = 0;
        float mv0, mv1, mv2, mv3, lv0, lv1, lv2, lv3;
        float4 ev;
        #pragma unroll
        for (int j = 0; j < 4; ++j) {
            int u = uq * 4 + j;
            const float4* q4 = (const float4*)&qs[u][0];
            float s = 0.0f;
            #pragma unroll
            for (int cc = 0; cc < 16; ++cc) {
                float4 qv = q4[cc];
                s += qv.x * kreg[cc].x + qv.y * kreg[cc].y
                   + qv.z * kreg[cc].z + qv.w * kreg[cc].w;
            }
            s *= 0.125f;   // 1/sqrt(64)
            float m = s;
            #pragma unroll
            for (int off = 32; off >= 1; off >>= 1)
                m = fmaxf(m, __shfl_xor(m, off, 64));
            float e = __expf(s - m);
            float ls = e;
            #pragma unroll
            for (int off = 32; off >= 1; off >>= 1)
                ls += __shfl_xor(ls, off, 64);
            if (j == 0) { mv0 = m; lv0 = ls; ev.x = e; }
            if (j == 1) { mv1 = m; lv1 = ls; ev.y = e; }
            if (j == 2) { mv2 = m; lv2 = ls; ev.z = e; }
            if (j == 3) { mv3 = m; lv3 = ls; ev.w = e; }
        }
        e4buf[w][lane] = ev;
        asm volatile("s_waitcnt lgkmcnt(0)" ::: "memory");
        #pragma unroll
        for (int l2 = 0; l2 < 64; ++l2) {      // FULL unroll: vcol static
            float4 e = e4buf[w][l2];
            float  v = vcol[l2];
            o0 += e.x * v; o1 += e.y * v; o2 += e.z * v; o3 += e.w * v;
        }
        oarea[w][uq * 4 + 0][lane] = o0;
        oarea[w][uq * 4 + 1][lane] = o1;
        oarea[w][uq * 4 + 2][lane] = o2;
        oarea[w][uq * 4 + 3][lane] = o3;
        if (lane == 0) {
            mlarea[w][uq * 4 + 0][0] = mv0; mlarea[w][uq * 4 + 0][1] = lv0;
            mlarea[w][uq * 4 + 1][0] = mv1; mlarea[w][uq * 4 + 1][1] = lv1;
            mlarea[w][uq * 4 + 2][0] = mv2; mlarea[w][uq * 4 + 2][1] = lv2;
            mlarea[w][uq * 4 + 3][0] = mv3; mlarea[w][uq * 4 + 3][1] = lv3;
        }
    }
    __syncthreads();

    for (int i = t; i < QH * DD; i += 256) {
        int u = i >> 6, d = i & 63;
        float m0 = mlarea[0][u][0], m1 = mlarea[1][u][0];
        float m2 = mlarea[2][u][0], m3 = mlarea[3][u][0];
        float mb = fmaxf(fmaxf(m0, m1), fmaxf(m2, m3));
        float s0 = __expf(m0 - mb), s1 = __expf(m1 - mb);
        float s2 = __expf(m2 - mb), s3 = __expf(m3 - mb);
        float ob = oarea[0][u][d] * s0 + oarea[1][u][d] * s1
                 + oarea[2][u][d] * s2 + oarea[3][u][d] * s3;
        int gu = u0 + u;
        po[((size_t)(bh * NT + gu) * NCH + c) * DD + d] = ob;
        if (d == 0) {
            float lb = mlarea[0][u][1] * s0 + mlarea[1][u][1] * s1
                     + mlarea[2][u][1] * s2 + mlarea[3][u][1] * s3;
            pml[(bh * NT + gu) * NCH + c] = make_float2(mb, lb);
        }
    }
}

// ---------------------------------------------------------------------------
// Kernel 4: merge chunk partials. One wave per (bh,u), lane = d.
// ---------------------------------------------------------------------------
__global__ __launch_bounds__(256) void merge_kernel(
        const float2* __restrict__ pml, const float* __restrict__ po,
        float* __restrict__ out) {
    int wid  = blockIdx.x * 4 + (threadIdx.x >> 6);
    int lane = threadIdx.x & 63;
    int u  = wid % NT;
    int bh = wid / NT;
    int h = bh & (HH - 1), b = bh >> 3;
    int base = (bh * NT + u) * NCH;

    float m = -INFINITY;
    #pragma unroll
    for (int cc = 0; cc < NCH; ++cc) m = fmaxf(m, pml[base + cc].x);
    float lsum = 0.0f, o = 0.0f;
    #pragma unroll
    for (int cc = 0; cc < NCH; ++cc) {
        float2 ml = pml[base + cc];
        float sc = __expf(ml.x - m);
        lsum += ml.y * sc;
        o    += po[(size_t)(base + cc) * DD + lane] * sc;
    }
    out[(((size_t)b * NT + u) * HH + h) * DD + lane] = o / lsum;
}

extern "C" void kernel_launch(void* const* d_in, const int* in_sizes, int n_in,
                              void* d_out, int out_size, void* d_ws, size_t ws_size,
                              hipStream_t stream) {
    const float* Q   = (const float*)d_in[0];
    const float* K   = (const float*)d_in[1];
    const float* V   = (const float*)d_in[2];
    const int*   idx = (const int*)d_in[3];
    float* out = (float*)d_out;

    char* ws = (char*)d_ws;
    float*  M    = (float*)ws;                        ws += (size_t)BB * HH * LL * sizeof(float);
    int*    topi = (int*)ws;                          ws += (size_t)BB * HH * NT * sizeof(int);
    float2* pml  = (float2*)ws;                       ws += (size_t)BB * HH * NT * NCH * sizeof(float2);
    float*  po   = (float*)ws;                        // 2.62 MB

    hipLaunchKernelGGL(compute_m_kernel, dim3(BB * LL), dim3(256), 0, stream,
                       Q, K, idx, M);
    hipLaunchKernelGGL(topk_kernel, dim3(BB * HH), dim3(256), 0, stream, M, topi);
    hipLaunchKernelGGL(attn_kernel, dim3(2 * BB * HH * NCH), dim3(256), 0, stream,
                       Q, K, V, topi, pml, po);
    hipLaunchKernelGGL(merge_kernel, dim3(BB * HH * NT / 4), dim3(256), 0, stream,
                       pml, po, out);
}

// Round 5
// 170.711 us; speedup vs baseline: 1.2721x; 1.0675x over previous
//
#include <hip/hip_runtime.h>
#include <hip/hip_bf16.h>

// Problem constants: B=4, L=2048, H=8, D=64, SAMPLE_K=N_TOP=40
#define BB 4
#define LL 2048
#define HH 8
#define DD 64
#define SK 40
#define NT 40
#define CH 256              // keys per attn chunk
#define NCH (LL / CH)       // 8 chunks per (b,h)
#define QH 20               // queries per attn block (40 split in 2)

#define WS 10               // samples per wave (4 waves x 10 = 40)

typedef float f4 __attribute__((ext_vector_type(4)));

// ---------------------------------------------------------------------------
// Kernel 1: M[bh][l] = max_s(q . k_{idx[l,s]}) - (sum_s q . k_{idx[l,s]}) / L
//
// Round 18: rounds 16/17 kept the lane->(head,quarter) map fixed and loaded
// each lane's fragment at stride 64B -> 64 distinct cache lines PER
// INSTRUCTION (4x the TCP transactions of the coalesced round-13 staging
// loads). That transaction cost, not pipeline depth, dominated (53us, VALU
// 14%, HBM 11%). This round re-maps lanes so the COALESCED layout is the
// consume layout: lane cw of each half-wave (half = sample of the pair)
// loads float4s {cw, cw+32, cw+64, cw+96} of the 2KB K row — four
// contiguous-per-half-wave dwordx4 (8 lines/half/instr, fully coalesced).
// float4 index f = cw+32k covers head (cw>>4)+2k, dims [4(cw&15),+4).
// Q is loaded with the same fragment map; each lane computes 4 partial dots
// (one per held head); each head reduces over its 16-lane group via
// shfl_xor 1/2/4/8. No LDS staging, no transpose.
// Loads forced with inline asm (descending vmcnt consume) as in round 17.
// ---------------------------------------------------------------------------
__global__ __launch_bounds__(256, 2) void compute_m_kernel(
        const float* __restrict__ Q, const float* __restrict__ K,
        const int* __restrict__ idx, float* __restrict__ M) {
    __shared__ float2 mlpart[4][HH];

    int blk = blockIdx.x;
    int x = blk & 7, g = blk >> 3;
    int b = x >> 1;                    // XCD pair -> batch (per-batch K = 4.2MB fits XCD L2)
    int l = (g << 1) | (x & 1);
    int t = threadIdx.x;
    int lane = t & 63, w = t >> 6;
    int hw   = lane >> 5;              // which sample of the pair
    int cw   = lane & 31;
    int hpar = cw >> 4;                // head parity this lane handles

    // Q fragments, same map as K: float4 {cw, cw+32, cw+64, cw+96} of row l
    const float* Qrow = Q + ((size_t)b * LL + l) * 512 + cw * 4;
    f4 qk0 = *(const f4*)(Qrow);
    f4 qk1 = *(const f4*)(Qrow + 128);
    f4 qk2 = *(const f4*)(Qrow + 256);
    f4 qk3 = *(const f4*)(Qrow + 384);

    const float* Kb = K + (size_t)b * LL * 512 + cw * 4;
    const int* ib = idx + (size_t)l * SK + w * WS + hw;

    int ks0 = ib[0], ks1 = ib[2], ks2 = ib[4], ks3 = ib[6], ks4 = ib[8];
    const float* s0 = Kb + (size_t)ks0 * 512;
    const float* s1 = Kb + (size_t)ks1 * 512;
    const float* s2 = Kb + (size_t)ks2 * 512;
    const float* s3 = Kb + (size_t)ks3 * 512;
    const float* s4 = Kb + (size_t)ks4 * 512;

    // Drain compiler-tracked loads (Q, idx) BEFORE the asm pipeline so the
    // compiler's own vmcnt waits land here, not mid-pipeline.
    asm volatile("" : "+v"(qk0), "+v"(qk1), "+v"(qk2), "+v"(qk3));

    f4 k0a, k0b, k0c, k0d, k1a, k1b, k1c, k1d, k2a, k2b, k2c, k2d;
    f4 k3a, k3b, k3c, k3d, k4a, k4b, k4c, k4d;

    // Four dwordx4 per row at byte offsets 0/512/1024/1536: contiguous per
    // half-wave (lanes 0-31 cover 512B), 8 lines per half per instruction.
    #define LOADP(KA, KB_, KC, KD, SRC)                                         \
        asm volatile("global_load_dwordx4 %0, %4, off\n"                        \
                     "global_load_dwordx4 %1, %4, off offset:512\n"             \
                     "global_load_dwordx4 %2, %4, off offset:1024\n"            \
                     "global_load_dwordx4 %3, %4, off offset:1536"              \
                     : "=&v"(KA), "=&v"(KB_), "=&v"(KC), "=&v"(KD)              \
                     : "v"(SRC))

    LOADP(k0a, k0b, k0c, k0d, s0);
    LOADP(k1a, k1b, k1c, k1d, s1);
    LOADP(k2a, k2b, k2c, k2d, s2);
    LOADP(k3a, k3b, k3c, k3d, s3);
    LOADP(k4a, k4b, k4c, k4d, s4);
    #undef LOADP

    float mx0 = -INFINITY, mx1 = -INFINITY, mx2 = -INFINITY, mx3 = -INFINITY;
    float sm0 = 0.0f, sm1 = 0.0f, sm2 = 0.0f, sm3 = 0.0f;

    // Per pair: 4 partial dots (head hpar+2k), each reduced over the 16-lane
    // group (xor 1/2/4/8 stay inside the group: bits 4,5 of lane untouched).
    #define CONSUME(KA, KB_, KC, KD, WAIT) do {                                 \
        asm volatile(WAIT : "+v"(KA), "+v"(KB_), "+v"(KC), "+v"(KD));           \
        float p0 = qk0.x*KA.x + qk0.y*KA.y + qk0.z*KA.z + qk0.w*KA.w;           \
        float p1 = qk1.x*KB_.x + qk1.y*KB_.y + qk1.z*KB_.z + qk1.w*KB_.w;       \
        float p2 = qk2.x*KC.x + qk2.y*KC.y + qk2.z*KC.z + qk2.w*KC.w;           \
        float p3 = qk3.x*KD.x + qk3.y*KD.y + qk3.z*KD.z + qk3.w*KD.w;           \
        p0 += __shfl_xor(p0, 1, 64);  p1 += __shfl_xor(p1, 1, 64);              \
        p2 += __shfl_xor(p2, 1, 64);  p3 += __shfl_xor(p3, 1, 64);              \
        p0 += __shfl_xor(p0, 2, 64);  p1 += __shfl_xor(p1, 2, 64);              \
        p2 += __shfl_xor(p2, 2, 64);  p3 += __shfl_xor(p3, 2, 64);              \
        p0 += __shfl_xor(p0, 4, 64);  p1 += __shfl_xor(p1, 4, 64);              \
        p2 += __shfl_xor(p2, 4, 64);  p3 += __shfl_xor(p3, 4, 64);              \
        p0 += __shfl_xor(p0, 8, 64);  p1 += __shfl_xor(p1, 8, 64);              \
        p2 += __shfl_xor(p2, 8, 64);  p3 += __shfl_xor(p3, 8, 64);              \
        mx0 = fmaxf(mx0, p0); sm0 += p0;                                        \
        mx1 = fmaxf(mx1, p1); sm1 += p1;                                        \
        mx2 = fmaxf(mx2, p2); sm2 += p2;                                        \
        mx3 = fmaxf(mx3, p3); sm3 += p3;                                        \
    } while (0)

    CONSUME(k0a, k0b, k0c, k0d, "s_waitcnt vmcnt(16)");
    CONSUME(k1a, k1b, k1c, k1d, "s_waitcnt vmcnt(12)");
    CONSUME(k2a, k2b, k2c, k2d, "s_waitcnt vmcnt(8)");
    CONSUME(k3a, k3b, k3c, k3d, "s_waitcnt vmcnt(4)");
    CONSUME(k4a, k4b, k4c, k4d, "s_waitcnt vmcnt(0)");
    #undef CONSUME

    // merge the two sample-halves (lane ^ 32 holds the other sample's stats)
    mx0 = fmaxf(mx0, __shfl_xor(mx0, 32, 64)); sm0 += __shfl_xor(sm0, 32, 64);
    mx1 = fmaxf(mx1, __shfl_xor(mx1, 32, 64)); sm1 += __shfl_xor(sm1, 32, 64);
    mx2 = fmaxf(mx2, __shfl_xor(mx2, 32, 64)); sm2 += __shfl_xor(sm2, 32, 64);
    mx3 = fmaxf(mx3, __shfl_xor(mx3, 32, 64)); sm3 += __shfl_xor(sm3, 32, 64);

    if (hw == 0 && (cw & 15) == 0) {   // lanes 0 (heads 0,2,4,6) and 16 (1,3,5,7)
        mlpart[w][hpar + 0] = make_float2(mx0, sm0);
        mlpart[w][hpar + 2] = make_float2(mx1, sm1);
        mlpart[w][hpar + 4] = make_float2(mx2, sm2);
        mlpart[w][hpar + 6] = make_float2(mx3, sm3);
    }
    __syncthreads();

    if (t < HH) {
        float MX = -INFINITY, SM = 0.0f;
        #pragma unroll
        for (int w2 = 0; w2 < 4; ++w2) {
            float2 ml = mlpart[w2][t];
            MX = fmaxf(MX, ml.x);
            SM += ml.y;
        }
        M[((size_t)b * HH + t) * LL + l] = MX - SM * (1.0f / (float)LL);
    }
}

// ---------------------------------------------------------------------------
// Kernel 2: top-40 per (b,h), lower index wins ties. Incremental argmax.
// ---------------------------------------------------------------------------
__global__ __launch_bounds__(256) void topk_kernel(const float* __restrict__ M,
                                                   int* __restrict__ topi) {
    __shared__ unsigned long long keys[LL];   // 16 KB
    __shared__ unsigned long long wmax[4];
    __shared__ int win;
    int bh = blockIdx.x;
    int t  = threadIdx.x;
    int lane = t & 63, w = t >> 6;

    unsigned long long kmax = 0ULL;
    #pragma unroll
    for (int j = 0; j < 8; ++j) {
        int i = t + 256 * j;
        unsigned int bits = __float_as_uint(M[(size_t)bh * LL + i]);
        bits = (bits & 0x80000000u) ? ~bits : (bits | 0x80000000u);
        unsigned long long k = ((unsigned long long)bits << 11)
                             | (unsigned int)(LL - 1 - i);
        keys[i] = k;
        if (k > kmax) kmax = k;
    }
    __syncthreads();

    for (int u = 0; u < NT; ++u) {
        unsigned long long k = kmax;
        #pragma unroll
        for (int off = 32; off >= 1; off >>= 1) {
            unsigned long long o = __shfl_xor(k, off, 64);
            if (o > k) k = o;
        }
        if (lane == 0) wmax[w] = k;
        __syncthreads();
        if (t == 0) {
            unsigned long long k0 = wmax[0];
            if (wmax[1] > k0) k0 = wmax[1];
            if (wmax[2] > k0) k0 = wmax[2];
            if (wmax[3] > k0) k0 = wmax[3];
            int i = (LL - 1) - (int)(k0 & 0x7FF);
            topi[bh * NT + u] = i;
            keys[i] = 0ULL;
            win = i;
        }
        __syncthreads();
        if ((win & 255) == t) {          // only the owner rescans
            kmax = 0ULL;
            #pragma unroll
            for (int j = 0; j < 8; ++j) {
                unsigned long long kk = keys[t + 256 * j];
                if (kk > kmax) kmax = kk;
            }
        }
    }
}

// ---------------------------------------------------------------------------
// Kernel 3: flash-chunked attention, query-split.
// __launch_bounds__(256,3) keeps kreg/vcol in registers (round 7 spill fix).
// (m,l) packed float2 store (round 8 granule-waste fix).
// ---------------------------------------------------------------------------
__global__ __launch_bounds__(256, 3) void attn_kernel(
        const float* __restrict__ Q, const float* __restrict__ K,
        const float* __restrict__ V, const int* __restrict__ topi,
        float2* __restrict__ pml, float* __restrict__ po) {
    __shared__ float  qs[QH][DD];        //  5120 B
    __shared__ float4 e4buf[4][64];      //  4096 B
    __shared__ float  oarea[4][QH][DD];  // 20480 B
    __shared__ float  mlarea[4][QH][2];  //   640 B

    int blk = blockIdx.x;
    int qh  = blk >> 8;                  // 0/1 query half
    int cc2 = blk & 255;
    int c   = cc2 & (NCH - 1);
    int bh  = cc2 >> 3;
    int h = bh & (HH - 1), b = bh >> 3;
    int t = threadIdx.x, lane = t & 63, w = t >> 6;
    int u0 = qh * QH;

    for (int i = t; i < QH * DD; i += 256) {
        int u = i >> 6, d = i & 63;
        int lq = topi[bh * NT + u0 + u];
        qs[u][d] = Q[(((size_t)b * LL + lq) * HH + h) * DD + d];
    }

    int key = c * CH + w * 64 + lane;
    const float4* kr = (const float4*)&K[(((size_t)b * LL + key) * HH + h) * DD];
    float4 kreg[16];
    #pragma unroll
    for (int j = 0; j < 16; ++j) kreg[j] = kr[j];

    float vcol[64];
    const float* vb = &V[(((size_t)b * LL + c * CH + w * 64) * HH + h) * DD + lane];
    #pragma unroll
    for (int j = 0; j < 64; ++j) vcol[j] = vb[(size_t)j * HH * DD];

    __syncthreads();   // qs ready

    for (int uq = 0; uq < QH / 4; ++uq) {
        float o0 = 0, o1 = 0, o2 = 0, o3 = 0;
        float mv0, mv1, mv2, mv3, lv0, lv1, lv2, lv3;
        float4 ev;
        #pragma unroll
        for (int j = 0; j < 4; ++j) {
            int u = uq * 4 + j;
            const float4* q4 = (const float4*)&qs[u][0];
            float s = 0.0f;
            #pragma unroll
            for (int cc = 0; cc < 16; ++cc) {
                float4 qv = q4[cc];
                s += qv.x * kreg[cc].x + qv.y * kreg[cc].y
                   + qv.z * kreg[cc].z + qv.w * kreg[cc].w;
            }
            s *= 0.125f;   // 1/sqrt(64)
            float m = s;
            #pragma unroll
            for (int off = 32; off >= 1; off >>= 1)
                m = fmaxf(m, __shfl_xor(m, off, 64));
            float e = __expf(s - m);
            float ls = e;
            #pragma unroll
            for (int off = 32; off >= 1; off >>= 1)
                ls += __shfl_xor(ls, off, 64);
            if (j == 0) { mv0 = m; lv0 = ls; ev.x = e; }
            if (j == 1) { mv1 = m; lv1 = ls; ev.y = e; }
            if (j == 2) { mv2 = m; lv2 = ls; ev.z = e; }
            if (j == 3) { mv3 = m; lv3 = ls; ev.w = e; }
        }
        e4buf[w][lane] = ev;
        asm volatile("s_waitcnt lgkmcnt(0)" ::: "memory");
        #pragma unroll
        for (int l2 = 0; l2 < 64; ++l2) {      // FULL unroll: vcol static
            float4 e = e4buf[w][l2];
            float  v = vcol[l2];
            o0 += e.x * v; o1 += e.y * v; o2 += e.z * v; o3 += e.w * v;
        }
        oarea[w][uq * 4 + 0][lane] = o0;
        oarea[w][uq * 4 + 1][lane] = o1;
        oarea[w][uq * 4 + 2][lane] = o2;
        oarea[w][uq * 4 + 3][lane] = o3;
        if (lane == 0) {
            mlarea[w][uq * 4 + 0][0] = mv0; mlarea[w][uq * 4 + 0][1] = lv0;
            mlarea[w][uq * 4 + 1][0] = mv1; mlarea[w][uq * 4 + 1][1] = lv1;
            mlarea[w][uq * 4 + 2][0] = mv2; mlarea[w][uq * 4 + 2][1] = lv2;
            mlarea[w][uq * 4 + 3][0] = mv3; mlarea[w][uq * 4 + 3][1] = lv3;
        }
    }
    __syncthreads();

    for (int i = t; i < QH * DD; i += 256) {
        int u = i >> 6, d = i & 63;
        float m0 = mlarea[0][u][0], m1 = mlarea[1][u][0];
        float m2 = mlarea[2][u][0], m3 = mlarea[3][u][0];
        float mb = fmaxf(fmaxf(m0, m1), fmaxf(m2, m3));
        float s0 = __expf(m0 - mb), s1 = __expf(m1 - mb);
        float s2 = __expf(m2 - mb), s3 = __expf(m3 - mb);
        float ob = oarea[0][u][d] * s0 + oarea[1][u][d] * s1
                 + oarea[2][u][d] * s2 + oarea[3][u][d] * s3;
        int gu = u0 + u;
        po[((size_t)(bh * NT + gu) * NCH + c) * DD + d] = ob;
        if (d == 0) {
            float lb = mlarea[0][u][1] * s0 + mlarea[1][u][1] * s1
                     + mlarea[2][u][1] * s2 + mlarea[3][u][1] * s3;
            pml[(bh * NT + gu) * NCH + c] = make_float2(mb, lb);
        }
    }
}

// ---------------------------------------------------------------------------
// Kernel 4: merge chunk partials. One wave per (bh,u), lane = d.
// ---------------------------------------------------------------------------
__global__ __launch_bounds__(256) void merge_kernel(
        const float2* __restrict__ pml, const float* __restrict__ po,
        float* __restrict__ out) {
    int wid  = blockIdx.x * 4 + (threadIdx.x >> 6);
    int lane = threadIdx.x & 63;
    int u  = wid % NT;
    int bh = wid / NT;
    int h = bh & (HH - 1), b = bh >> 3;
    int base = (bh * NT + u) * NCH;

    float m = -INFINITY;
    #pragma unroll
    for (int cc = 0; cc < NCH; ++cc) m = fmaxf(m, pml[base + cc].x);
    float lsum = 0.0f, o = 0.0f;
    #pragma unroll
    for (int cc = 0; cc < NCH; ++cc) {
        float2 ml = pml[base + cc];
        float sc = __expf(ml.x - m);
        lsum += ml.y * sc;
        o    += po[(size_t)(base + cc) * DD + lane] * sc;
    }
    out[(((size_t)b * NT + u) * HH + h) * DD + lane] = o / lsum;
}

extern "C" void kernel_launch(void* const* d_in, const int* in_sizes, int n_in,
                              void* d_out, int out_size, void* d_ws, size_t ws_size,
                              hipStream_t stream) {
    const float* Q   = (const float*)d_in[0];
    const float* K   = (const float*)d_in[1];
    const float* V   = (const float*)d_in[2];
    const int*   idx = (const int*)d_in[3];
    float* out = (float*)d_out;

    char* ws = (char*)d_ws;
    float*  M    = (float*)ws;                        ws += (size_t)BB * HH * LL * sizeof(float);
    int*    topi = (int*)ws;                          ws += (size_t)BB * HH * NT * sizeof(int);
    float2* pml  = (float2*)ws;                       ws += (size_t)BB * HH * NT * NCH * sizeof(float2);
    float*  po   = (float*)ws;                        // 2.62 MB

    hipLaunchKernelGGL(compute_m_kernel, dim3(BB * LL), dim3(256), 0, stream,
                       Q, K, idx, M);
    hipLaunchKernelGGL(topk_kernel, dim3(BB * HH), dim3(256), 0, stream, M, topi);
    hipLaunchKernelGGL(attn_kernel, dim3(2 * BB * HH * NCH), dim3(256), 0, stream,
                       Q, K, V, topi, pml, po);
    hipLaunchKernelGGL(merge_kernel, dim3(BB * HH * NT / 4), dim3(256), 0, stream,
                       pml, po, out);
}

// Round 6
// 166.829 us; speedup vs baseline: 1.3017x; 1.0233x over previous
//
#include <hip/hip_runtime.h>
#include <hip/hip_bf16.h>

// Problem constants: B=4, L=2048, H=8, D=64, SAMPLE_K=N_TOP=40
#define BB 4
#define LL 2048
#define HH 8
#define DD 64
#define SK 40
#define NT 40
#define CH 256              // keys per attn chunk
#define NCH (LL / CH)       // 8 chunks per (b,h)
#define QH 20               // queries per attn block (40 split in 2)

#define WS 10               // samples per wave (4 waves x 10 = 40)

typedef float f4 __attribute__((ext_vector_type(4)));

// ---------------------------------------------------------------------------
// Kernel 1: M[bh][l] = max_s(q . k_{idx[l,s]}) - (sum_s q . k_{idx[l,s]}) / L
//
// Round 19: whole-wave-per-row decomposition. One K row (2KB) = 64 lanes x
// 32B = exactly 2 coalesced dwordx4 per row. Lane's floats [lane*8, +8) are
// head lane>>3, dims 8*(lane&7)..+7 — and Q's fragment for that (head,dim)
// range sits at the SAME row offset lane*8 (identity map). Per sample:
// 8 FMAs + 3 shfl_xor (reduce over the 8-lane head group). 10 samples per
// wave, depth-6 rolling asm pipeline (issue rows 0-5 up front; consume i /
// issue i+5; steady-state s_waitcnt vmcnt(10), tail 8/6/4/2/0).
// Live K data <= 12 f4 = 48 VGPRs — small enough that regalloc cannot
// profitably spill it (rounds 16-18: 80-reg live sets got silently broken,
// VGPR_Count stuck at 52). Shfl count 88 -> 34 per wave.
// ---------------------------------------------------------------------------
__global__ __launch_bounds__(256, 3) void compute_m_kernel(
        const float* __restrict__ Q, const float* __restrict__ K,
        const int* __restrict__ idx, float* __restrict__ M) {
    __shared__ float2 mlpart[4][HH];

    int blk = blockIdx.x;
    int x = blk & 7, g = blk >> 3;
    int b = x >> 1;                    // XCD pair -> batch (per-batch K = 4.2MB fits XCD L2)
    int l = (g << 1) | (x & 1);
    int t = threadIdx.x;
    int lane = t & 63, w = t >> 6;
    int grp  = lane >> 3;              // head this lane contributes to

    // Q fragment: same identity map as K rows — floats [lane*8, +8) of row l
    const float* Qrow = Q + ((size_t)b * LL + l) * 512 + lane * 8;
    f4 qa = *(const f4*)(Qrow);
    f4 qb = *(const f4*)(Qrow + 4);

    const float* Kb = K + (size_t)b * LL * 512 + lane * 8;
    const int* ib = idx + (size_t)l * SK + w * WS;

    int i0 = ib[0], i1 = ib[1], i2 = ib[2], i3 = ib[3], i4 = ib[4];
    int i5 = ib[5], i6 = ib[6], i7 = ib[7], i8 = ib[8], i9 = ib[9];
    const float* a0 = Kb + (size_t)i0 * 512;
    const float* a1 = Kb + (size_t)i1 * 512;
    const float* a2 = Kb + (size_t)i2 * 512;
    const float* a3 = Kb + (size_t)i3 * 512;
    const float* a4 = Kb + (size_t)i4 * 512;
    const float* a5 = Kb + (size_t)i5 * 512;
    const float* a6 = Kb + (size_t)i6 * 512;
    const float* a7 = Kb + (size_t)i7 * 512;
    const float* a8 = Kb + (size_t)i8 * 512;
    const float* a9 = Kb + (size_t)i9 * 512;

    // Drain compiler-tracked loads (Q, idx) BEFORE the asm pipeline so the
    // compiler's own vmcnt waits land here, not mid-pipeline.
    asm volatile("" : "+v"(qa), "+v"(qb));

    f4 A0, B0, A1, B1, A2, B2, A3, B3, A4, B4;
    f4 A5, B5, A6, B6, A7, B7, A8, B8, A9, B9;

    // One row = two coalesced dwordx4 (wave covers the full 2KB row).
    #define ISSUE(AV, BV, PTR)                                                  \
        asm volatile("global_load_dwordx4 %0, %2, off\n"                        \
                     "global_load_dwordx4 %1, %2, off offset:16"                \
                     : "=&v"(AV), "=&v"(BV) : "v"(PTR))

    float mx = -INFINITY, sm = 0.0f;

    #define CONS(AV, BV, WAIT) do {                                            \
        asm volatile(WAIT : "+v"(AV), "+v"(BV));                               \
        float p = qa.x*AV.x + qa.y*AV.y + qa.z*AV.z + qa.w*AV.w                \
                + qb.x*BV.x + qb.y*BV.y + qb.z*BV.z + qb.w*BV.w;               \
        p += __shfl_xor(p, 1, 64);                                             \
        p += __shfl_xor(p, 2, 64);                                             \
        p += __shfl_xor(p, 4, 64);                                             \
        mx = fmaxf(mx, p);                                                     \
        sm += p;                                                               \
    } while (0)

    ISSUE(A0, B0, a0); ISSUE(A1, B1, a1); ISSUE(A2, B2, a2);
    ISSUE(A3, B3, a3); ISSUE(A4, B4, a4);
    ISSUE(A5, B5, a5); CONS(A0, B0, "s_waitcnt vmcnt(10)");
    ISSUE(A6, B6, a6); CONS(A1, B1, "s_waitcnt vmcnt(10)");
    ISSUE(A7, B7, a7); CONS(A2, B2, "s_waitcnt vmcnt(10)");
    ISSUE(A8, B8, a8); CONS(A3, B3, "s_waitcnt vmcnt(10)");
    ISSUE(A9, B9, a9); CONS(A4, B4, "s_waitcnt vmcnt(10)");
    CONS(A5, B5, "s_waitcnt vmcnt(8)");
    CONS(A6, B6, "s_waitcnt vmcnt(6)");
    CONS(A7, B7, "s_waitcnt vmcnt(4)");
    CONS(A8, B8, "s_waitcnt vmcnt(2)");
    CONS(A9, B9, "s_waitcnt vmcnt(0)");
    #undef ISSUE
    #undef CONS

    // 8 lanes per wave (one per head group) hold that head's (mx, sm)
    if ((lane & 7) == 0)
        mlpart[w][grp] = make_float2(mx, sm);
    __syncthreads();

    if (t < HH) {
        float MX = -INFINITY, SM = 0.0f;
        #pragma unroll
        for (int w2 = 0; w2 < 4; ++w2) {
            float2 ml = mlpart[w2][t];
            MX = fmaxf(MX, ml.x);
            SM += ml.y;
        }
        M[((size_t)b * HH + t) * LL + l] = MX - SM * (1.0f / (float)LL);
    }
}

// ---------------------------------------------------------------------------
// Kernel 2: top-40 per (b,h), lower index wins ties. Incremental argmax.
// ---------------------------------------------------------------------------
__global__ __launch_bounds__(256) void topk_kernel(const float* __restrict__ M,
                                                   int* __restrict__ topi) {
    __shared__ unsigned long long keys[LL];   // 16 KB
    __shared__ unsigned long long wmax[4];
    __shared__ int win;
    int bh = blockIdx.x;
    int t  = threadIdx.x;
    int lane = t & 63, w = t >> 6;

    unsigned long long kmax = 0ULL;
    #pragma unroll
    for (int j = 0; j < 8; ++j) {
        int i = t + 256 * j;
        unsigned int bits = __float_as_uint(M[(size_t)bh * LL + i]);
        bits = (bits & 0x80000000u) ? ~bits : (bits | 0x80000000u);
        unsigned long long k = ((unsigned long long)bits << 11)
                             | (unsigned int)(LL - 1 - i);
        keys[i] = k;
        if (k > kmax) kmax = k;
    }
    __syncthreads();

    for (int u = 0; u < NT; ++u) {
        unsigned long long k = kmax;
        #pragma unroll
        for (int off = 32; off >= 1; off >>= 1) {
            unsigned long long o = __shfl_xor(k, off, 64);
            if (o > k) k = o;
        }
        if (lane == 0) wmax[w] = k;
        __syncthreads();
        if (t == 0) {
            unsigned long long k0 = wmax[0];
            if (wmax[1] > k0) k0 = wmax[1];
            if (wmax[2] > k0) k0 = wmax[2];
            if (wmax[3] > k0) k0 = wmax[3];
            int i = (LL - 1) - (int)(k0 & 0x7FF);
            topi[bh * NT + u] = i;
            keys[i] = 0ULL;
            win = i;
        }
        __syncthreads();
        if ((win & 255) == t) {          // only the owner rescans
            kmax = 0ULL;
            #pragma unroll
            for (int j = 0; j < 8; ++j) {
                unsigned long long kk = keys[t + 256 * j];
                if (kk > kmax) kmax = kk;
            }
        }
    }
}

// ---------------------------------------------------------------------------
// Kernel 3: flash-chunked attention, query-split.
// __launch_bounds__(256,3) keeps kreg/vcol in registers (round 7 spill fix).
// (m,l) packed float2 store (round 8 granule-waste fix).
// ---------------------------------------------------------------------------
__global__ __launch_bounds__(256, 3) void attn_kernel(
        const float* __restrict__ Q, const float* __restrict__ K,
        const float* __restrict__ V, const int* __restrict__ topi,
        float2* __restrict__ pml, float* __restrict__ po) {
    __shared__ float  qs[QH][DD];        //  5120 B
    __shared__ float4 e4buf[4][64];      //  4096 B
    __shared__ float  oarea[4][QH][DD];  // 20480 B
    __shared__ float  mlarea[4][QH][2];  //   640 B

    int blk = blockIdx.x;
    int qh  = blk >> 8;                  // 0/1 query half
    int cc2 = blk & 255;
    int c   = cc2 & (NCH - 1);
    int bh  = cc2 >> 3;
    int h = bh & (HH - 1), b = bh >> 3;
    int t = threadIdx.x, lane = t & 63, w = t >> 6;
    int u0 = qh * QH;

    for (int i = t; i < QH * DD; i += 256) {
        int u = i >> 6, d = i & 63;
        int lq = topi[bh * NT + u0 + u];
        qs[u][d] = Q[(((size_t)b * LL + lq) * HH + h) * DD + d];
    }

    int key = c * CH + w * 64 + lane;
    const float4* kr = (const float4*)&K[(((size_t)b * LL + key) * HH + h) * DD];
    float4 kreg[16];
    #pragma unroll
    for (int j = 0; j < 16; ++j) kreg[j] = kr[j];

    float vcol[64];
    const float* vb = &V[(((size_t)b * LL + c * CH + w * 64) * HH + h) * DD + lane];
    #pragma unroll
    for (int j = 0; j < 64; ++j) vcol[j] = vb[(size_t)j * HH * DD];

    __syncthreads();   // qs ready

    for (int uq = 0; uq < QH / 4; ++uq) {
        float o0 = 0, o1 = 0, o2 = 0, o3 = 0;
        float mv0, mv1, mv2, mv3, lv0, lv1, lv2, lv3;
        float4 ev;
        #pragma unroll
        for (int j = 0; j < 4; ++j) {
            int u = uq * 4 + j;
            const float4* q4 = (const float4*)&qs[u][0];
            float s = 0.0f;
            #pragma unroll
            for (int cc = 0; cc < 16; ++cc) {
                float4 qv = q4[cc];
                s += qv.x * kreg[cc].x + qv.y * kreg[cc].y
                   + qv.z * kreg[cc].z + qv.w * kreg[cc].w;
            }
            s *= 0.125f;   // 1/sqrt(64)
            float m = s;
            #pragma unroll
            for (int off = 32; off >= 1; off >>= 1)
                m = fmaxf(m, __shfl_xor(m, off, 64));
            float e = __expf(s - m);
            float ls = e;
            #pragma unroll
            for (int off = 32; off >= 1; off >>= 1)
                ls += __shfl_xor(ls, off, 64);
            if (j == 0) { mv0 = m; lv0 = ls; ev.x = e; }
            if (j == 1) { mv1 = m; lv1 = ls; ev.y = e; }
            if (j == 2) { mv2 = m; lv2 = ls; ev.z = e; }
            if (j == 3) { mv3 = m; lv3 = ls; ev.w = e; }
        }
        e4buf[w][lane] = ev;
        asm volatile("s_waitcnt lgkmcnt(0)" ::: "memory");
        #pragma unroll
        for (int l2 = 0; l2 < 64; ++l2) {      // FULL unroll: vcol static
            float4 e = e4buf[w][l2];
            float  v = vcol[l2];
            o0 += e.x * v; o1 += e.y * v; o2 += e.z * v; o3 += e.w * v;
        }
        oarea[w][uq * 4 + 0][lane] = o0;
        oarea[w][uq * 4 + 1][lane] = o1;
        oarea[w][uq * 4 + 2][lane] = o2;
        oarea[w][uq * 4 + 3][lane] = o3;
        if (lane == 0) {
            mlarea[w][uq * 4 + 0][0] = mv0; mlarea[w][uq * 4 + 0][1] = lv0;
            mlarea[w][uq * 4 + 1][0] = mv1; mlarea[w][uq * 4 + 1][1] = lv1;
            mlarea[w][uq * 4 + 2][0] = mv2; mlarea[w][uq * 4 + 2][1] = lv2;
            mlarea[w][uq * 4 + 3][0] = mv3; mlarea[w][uq * 4 + 3][1] = lv3;
        }
    }
    __syncthreads();

    for (int i = t; i < QH * DD; i += 256) {
        int u = i >> 6, d = i & 63;
        float m0 = mlarea[0][u][0], m1 = mlarea[1][u][0];
        float m2 = mlarea[2][u][0], m3 = mlarea[3][u][0];
        float mb = fmaxf(fmaxf(m0, m1), fmaxf(m2, m3));
        float s0 = __expf(m0 - mb), s1 = __expf(m1 - mb);
        float s2 = __expf(m2 - mb), s3 = __expf(m3 - mb);
        float ob = oarea[0][u][d] * s0 + oarea[1][u][d] * s1
                 + oarea[2][u][d] * s2 + oarea[3][u][d] * s3;
        int gu = u0 + u;
        po[((size_t)(bh * NT + gu) * NCH + c) * DD + d] = ob;
        if (d == 0) {
            float lb = mlarea[0][u][1] * s0 + mlarea[1][u][1] * s1
                     + mlarea[2][u][1] * s2 + mlarea[3][u][1] * s3;
            pml[(bh * NT + gu) * NCH + c] = make_float2(mb, lb);
        }
    }
}

// ---------------------------------------------------------------------------
// Kernel 4: merge chunk partials. One wave per (bh,u), lane = d.
// ---------------------------------------------------------------------------
__global__ __launch_bounds__(256) void merge_kernel(
        const float2* __restrict__ pml, const float* __restrict__ po,
        float* __restrict__ out) {
    int wid  = blockIdx.x * 4 + (threadIdx.x >> 6);
    int lane = threadIdx.x & 63;
    int u  = wid % NT;
    int bh = wid / NT;
    int h = bh & (HH - 1), b = bh >> 3;
    int base = (bh * NT + u) * NCH;

    float m = -INFINITY;
    #pragma unroll
    for (int cc = 0; cc < NCH; ++cc) m = fmaxf(m, pml[base + cc].x);
    float lsum = 0.0f, o = 0.0f;
    #pragma unroll
    for (int cc = 0; cc < NCH; ++cc) {
        float2 ml = pml[base + cc];
        float sc = __expf(ml.x - m);
        lsum += ml.y * sc;
        o    += po[(size_t)(base + cc) * DD + lane] * sc;
    }
    out[(((size_t)b * NT + u) * HH + h) * DD + lane] = o / lsum;
}

extern "C" void kernel_launch(void* const* d_in, const int* in_sizes, int n_in,
                              void* d_out, int out_size, void* d_ws, size_t ws_size,
                              hipStream_t stream) {
    const float* Q   = (const float*)d_in[0];
    const float* K   = (const float*)d_in[1];
    const float* V   = (const float*)d_in[2];
    const int*   idx = (const int*)d_in[3];
    float* out = (float*)d_out;

    char* ws = (char*)d_ws;
    float*  M    = (float*)ws;                        ws += (size_t)BB * HH * LL * sizeof(float);
    int*    topi = (int*)ws;                          ws += (size_t)BB * HH * NT * sizeof(int);
    float2* pml  = (float2*)ws;                       ws += (size_t)BB * HH * NT * NCH * sizeof(float2);
    float*  po   = (float*)ws;                        // 2.62 MB

    hipLaunchKernelGGL(compute_m_kernel, dim3(BB * LL), dim3(256), 0, stream,
                       Q, K, idx, M);
    hipLaunchKernelGGL(topk_kernel, dim3(BB * HH), dim3(256), 0, stream, M, topi);
    hipLaunchKernelGGL(attn_kernel, dim3(2 * BB * HH * NCH), dim3(256), 0, stream,
                       Q, K, V, topi, pml, po);
    hipLaunchKernelGGL(merge_kernel, dim3(BB * HH * NT / 4), dim3(256), 0, stream,
                       pml, po, out);
}

// Round 7
// 165.876 us; speedup vs baseline: 1.3092x; 1.0057x over previous
//
#include <hip/hip_runtime.h>
#include <hip/hip_bf16.h>

// Problem constants: B=4, L=2048, H=8, D=64, SAMPLE_K=N_TOP=40
#define BB 4
#define LL 2048
#define HH 8
#define DD 64
#define SK 40
#define NT 40
#define CH 256              // keys per attn chunk
#define NCH (LL / CH)       // 8 chunks per (b,h)
#define QH 20               // queries per attn block (40 split in 2)

#define WS 10               // samples per wave (4 waves x 10 = 40)

typedef float f4 __attribute__((ext_vector_type(4)));

// ---------------------------------------------------------------------------
// Kernel 1: M[bh][l] = max_s(q . k_{idx[l,s]}) - (sum_s q . k_{idx[l,s]}) / L
//
// Round 19 (whole-wave-per-row): one K row (2KB) = 64 lanes x 32B = exactly
// 2 coalesced dwordx4 per row. Lane's floats [lane*8,+8) are head lane>>3,
// dims 8*(lane&7)..+7 — Q's fragment sits at the SAME offset (identity map).
// Per sample: 8 FMAs + 3 shfl_xor. Depth-6 rolling asm pipeline, steady
// vmcnt(10). Got 46 -> ~42us.
// Round 20: the residual ~20us is un-overlapped vmem wait — and occupancy
// was self-capped at 12 waves/CU by __launch_bounds__(256,3) (observed 32%).
// Per-wave VALU is ~13us/CU (matches VALUBusy 29% x 46us); L1 line-service
// floor ~17us/CU. Deep MLP (this pipeline) x high TLP (more waves) is what
// fills the L1 service pipe during other waves' VALU phases. VGPR=52 fits
// 6 waves/SIMD (cap 85) -> raise to __launch_bounds__(256,6): 24 waves/CU.
// ---------------------------------------------------------------------------
__global__ __launch_bounds__(256, 6) void compute_m_kernel(
        const float* __restrict__ Q, const float* __restrict__ K,
        const int* __restrict__ idx, float* __restrict__ M) {
    __shared__ float2 mlpart[4][HH];

    int blk = blockIdx.x;
    int x = blk & 7, g = blk >> 3;
    int b = x >> 1;                    // XCD pair -> batch (per-batch K = 4.2MB fits XCD L2)
    int l = (g << 1) | (x & 1);
    int t = threadIdx.x;
    int lane = t & 63, w = t >> 6;
    int grp  = lane >> 3;              // head this lane contributes to

    // Q fragment: same identity map as K rows — floats [lane*8, +8) of row l
    const float* Qrow = Q + ((size_t)b * LL + l) * 512 + lane * 8;
    f4 qa = *(const f4*)(Qrow);
    f4 qb = *(const f4*)(Qrow + 4);

    const float* Kb = K + (size_t)b * LL * 512 + lane * 8;
    const int* ib = idx + (size_t)l * SK + w * WS;

    int i0 = ib[0], i1 = ib[1], i2 = ib[2], i3 = ib[3], i4 = ib[4];
    int i5 = ib[5], i6 = ib[6], i7 = ib[7], i8 = ib[8], i9 = ib[9];
    const float* a0 = Kb + (size_t)i0 * 512;
    const float* a1 = Kb + (size_t)i1 * 512;
    const float* a2 = Kb + (size_t)i2 * 512;
    const float* a3 = Kb + (size_t)i3 * 512;
    const float* a4 = Kb + (size_t)i4 * 512;
    const float* a5 = Kb + (size_t)i5 * 512;
    const float* a6 = Kb + (size_t)i6 * 512;
    const float* a7 = Kb + (size_t)i7 * 512;
    const float* a8 = Kb + (size_t)i8 * 512;
    const float* a9 = Kb + (size_t)i9 * 512;

    // Drain compiler-tracked loads (Q, idx) BEFORE the asm pipeline so the
    // compiler's own vmcnt waits land here, not mid-pipeline.
    asm volatile("" : "+v"(qa), "+v"(qb));

    f4 A0, B0, A1, B1, A2, B2, A3, B3, A4, B4;
    f4 A5, B5, A6, B6, A7, B7, A8, B8, A9, B9;

    // One row = two coalesced dwordx4 (wave covers the full 2KB row).
    #define ISSUE(AV, BV, PTR)                                                  \
        asm volatile("global_load_dwordx4 %0, %2, off\n"                        \
                     "global_load_dwordx4 %1, %2, off offset:16"                \
                     : "=&v"(AV), "=&v"(BV) : "v"(PTR))

    float mx = -INFINITY, sm = 0.0f;

    #define CONS(AV, BV, WAIT) do {                                            \
        asm volatile(WAIT : "+v"(AV), "+v"(BV));                               \
        float p = qa.x*AV.x + qa.y*AV.y + qa.z*AV.z + qa.w*AV.w                \
                + qb.x*BV.x + qb.y*BV.y + qb.z*BV.z + qb.w*BV.w;               \
        p += __shfl_xor(p, 1, 64);                                             \
        p += __shfl_xor(p, 2, 64);                                             \
        p += __shfl_xor(p, 4, 64);                                             \
        mx = fmaxf(mx, p);                                                     \
        sm += p;                                                               \
    } while (0)

    ISSUE(A0, B0, a0); ISSUE(A1, B1, a1); ISSUE(A2, B2, a2);
    ISSUE(A3, B3, a3); ISSUE(A4, B4, a4);
    ISSUE(A5, B5, a5); CONS(A0, B0, "s_waitcnt vmcnt(10)");
    ISSUE(A6, B6, a6); CONS(A1, B1, "s_waitcnt vmcnt(10)");
    ISSUE(A7, B7, a7); CONS(A2, B2, "s_waitcnt vmcnt(10)");
    ISSUE(A8, B8, a8); CONS(A3, B3, "s_waitcnt vmcnt(10)");
    ISSUE(A9, B9, a9); CONS(A4, B4, "s_waitcnt vmcnt(10)");
    CONS(A5, B5, "s_waitcnt vmcnt(8)");
    CONS(A6, B6, "s_waitcnt vmcnt(6)");
    CONS(A7, B7, "s_waitcnt vmcnt(4)");
    CONS(A8, B8, "s_waitcnt vmcnt(2)");
    CONS(A9, B9, "s_waitcnt vmcnt(0)");
    #undef ISSUE
    #undef CONS

    // 8 lanes per wave (one per head group) hold that head's (mx, sm)
    if ((lane & 7) == 0)
        mlpart[w][grp] = make_float2(mx, sm);
    __syncthreads();

    if (t < HH) {
        float MX = -INFINITY, SM = 0.0f;
        #pragma unroll
        for (int w2 = 0; w2 < 4; ++w2) {
            float2 ml = mlpart[w2][t];
            MX = fmaxf(MX, ml.x);
            SM += ml.y;
        }
        M[((size_t)b * HH + t) * LL + l] = MX - SM * (1.0f / (float)LL);
    }
}

// ---------------------------------------------------------------------------
// Kernel 2: top-40 per (b,h), lower index wins ties. Incremental argmax.
// ---------------------------------------------------------------------------
__global__ __launch_bounds__(256) void topk_kernel(const float* __restrict__ M,
                                                   int* __restrict__ topi) {
    __shared__ unsigned long long keys[LL];   // 16 KB
    __shared__ unsigned long long wmax[4];
    __shared__ int win;
    int bh = blockIdx.x;
    int t  = threadIdx.x;
    int lane = t & 63, w = t >> 6;

    unsigned long long kmax = 0ULL;
    #pragma unroll
    for (int j = 0; j < 8; ++j) {
        int i = t + 256 * j;
        unsigned int bits = __float_as_uint(M[(size_t)bh * LL + i]);
        bits = (bits & 0x80000000u) ? ~bits : (bits | 0x80000000u);
        unsigned long long k = ((unsigned long long)bits << 11)
                             | (unsigned int)(LL - 1 - i);
        keys[i] = k;
        if (k > kmax) kmax = k;
    }
    __syncthreads();

    for (int u = 0; u < NT; ++u) {
        unsigned long long k = kmax;
        #pragma unroll
        for (int off = 32; off >= 1; off >>= 1) {
            unsigned long long o = __shfl_xor(k, off, 64);
            if (o > k) k = o;
        }
        if (lane == 0) wmax[w] = k;
        __syncthreads();
        if (t == 0) {
            unsigned long long k0 = wmax[0];
            if (wmax[1] > k0) k0 = wmax[1];
            if (wmax[2] > k0) k0 = wmax[2];
            if (wmax[3] > k0) k0 = wmax[3];
            int i = (LL - 1) - (int)(k0 & 0x7FF);
            topi[bh * NT + u] = i;
            keys[i] = 0ULL;
            win = i;
        }
        __syncthreads();
        if ((win & 255) == t) {          // only the owner rescans
            kmax = 0ULL;
            #pragma unroll
            for (int j = 0; j < 8; ++j) {
                unsigned long long kk = keys[t + 256 * j];
                if (kk > kmax) kmax = kk;
            }
        }
    }
}

// ---------------------------------------------------------------------------
// Kernel 3: flash-chunked attention, query-split.
// __launch_bounds__(256,3) keeps kreg/vcol in registers (round 7 spill fix).
// (m,l) packed float2 store (round 8 granule-waste fix).
// ---------------------------------------------------------------------------
__global__ __launch_bounds__(256, 3) void attn_kernel(
        const float* __restrict__ Q, const float* __restrict__ K,
        const float* __restrict__ V, const int* __restrict__ topi,
        float2* __restrict__ pml, float* __restrict__ po) {
    __shared__ float  qs[QH][DD];        //  5120 B
    __shared__ float4 e4buf[4][64];      //  4096 B
    __shared__ float  oarea[4][QH][DD];  // 20480 B
    __shared__ float  mlarea[4][QH][2];  //   640 B

    int blk = blockIdx.x;
    int qh  = blk >> 8;                  // 0/1 query half
    int cc2 = blk & 255;
    int c   = cc2 & (NCH - 1);
    int bh  = cc2 >> 3;
    int h = bh & (HH - 1), b = bh >> 3;
    int t = threadIdx.x, lane = t & 63, w = t >> 6;
    int u0 = qh * QH;

    for (int i = t; i < QH * DD; i += 256) {
        int u = i >> 6, d = i & 63;
        int lq = topi[bh * NT + u0 + u];
        qs[u][d] = Q[(((size_t)b * LL + lq) * HH + h) * DD + d];
    }

    int key = c * CH + w * 64 + lane;
    const float4* kr = (const float4*)&K[(((size_t)b * LL + key) * HH + h) * DD];
    float4 kreg[16];
    #pragma unroll
    for (int j = 0; j < 16; ++j) kreg[j] = kr[j];

    float vcol[64];
    const float* vb = &V[(((size_t)b * LL + c * CH + w * 64) * HH + h) * DD + lane];
    #pragma unroll
    for (int j = 0; j < 64; ++j) vcol[j] = vb[(size_t)j * HH * DD];

    __syncthreads();   // qs ready

    for (int uq = 0; uq < QH / 4; ++uq) {
        float o0 = 0, o1 = 0, o2 = 0, o3 = 0;
        float mv0, mv1, mv2, mv3, lv0, lv1, lv2, lv3;
        float4 ev;
        #pragma unroll
        for (int j = 0; j < 4; ++j) {
            int u = uq * 4 + j;
            const float4* q4 = (const float4*)&qs[u][0];
            float s = 0.0f;
            #pragma unroll
            for (int cc = 0; cc < 16; ++cc) {
                float4 qv = q4[cc];
                s += qv.x * kreg[cc].x + qv.y * kreg[cc].y
                   + qv.z * kreg[cc].z + qv.w * kreg[cc].w;
            }
            s *= 0.125f;   // 1/sqrt(64)
            float m = s;
            #pragma unroll
            for (int off = 32; off >= 1; off >>= 1)
                m = fmaxf(m, __shfl_xor(m, off, 64));
            float e = __expf(s - m);
            float ls = e;
            #pragma unroll
            for (int off = 32; off >= 1; off >>= 1)
                ls += __shfl_xor(ls, off, 64);
            if (j == 0) { mv0 = m; lv0 = ls; ev.x = e; }
            if (j == 1) { mv1 = m; lv1 = ls; ev.y = e; }
            if (j == 2) { mv2 = m; lv2 = ls; ev.z = e; }
            if (j == 3) { mv3 = m; lv3 = ls; ev.w = e; }
        }
        e4buf[w][lane] = ev;
        asm volatile("s_waitcnt lgkmcnt(0)" ::: "memory");
        #pragma unroll
        for (int l2 = 0; l2 < 64; ++l2) {      // FULL unroll: vcol static
            float4 e = e4buf[w][l2];
            float  v = vcol[l2];
            o0 += e.x * v; o1 += e.y * v; o2 += e.z * v; o3 += e.w * v;
        }
        oarea[w][uq * 4 + 0][lane] = o0;
        oarea[w][uq * 4 + 1][lane] = o1;
        oarea[w][uq * 4 + 2][lane] = o2;
        oarea[w][uq * 4 + 3][lane] = o3;
        if (lane == 0) {
            mlarea[w][uq * 4 + 0][0] = mv0; mlarea[w][uq * 4 + 0][1] = lv0;
            mlarea[w][uq * 4 + 1][0] = mv1; mlarea[w][uq * 4 + 1][1] = lv1;
            mlarea[w][uq * 4 + 2][0] = mv2; mlarea[w][uq * 4 + 2][1] = lv2;
            mlarea[w][uq * 4 + 3][0] = mv3; mlarea[w][uq * 4 + 3][1] = lv3;
        }
    }
    __syncthreads();

    for (int i = t; i < QH * DD; i += 256) {
        int u = i >> 6, d = i & 63;
        float m0 = mlarea[0][u][0], m1 = mlarea[1][u][0];
        float m2 = mlarea[2][u][0], m3 = mlarea[3][u][0];
        float mb = fmaxf(fmaxf(m0, m1), fmaxf(m2, m3));
        float s0 = __expf(m0 - mb), s1 = __expf(m1 - mb);
        float s2 = __expf(m2 - mb), s3 = __expf(m3 - mb);
        float ob = oarea[0][u][d] * s0 + oarea[1][u][d] * s1
                 + oarea[2][u][d] * s2 + oarea[3][u][d] * s3;
        int gu = u0 + u;
        po[((size_t)(bh * NT + gu) * NCH + c) * DD + d] = ob;
        if (d == 0) {
            float lb = mlarea[0][u][1] * s0 + mlarea[1][u][1] * s1
                     + mlarea[2][u][1] * s2 + mlarea[3][u][1] * s3;
            pml[(bh * NT + gu) * NCH + c] = make_float2(mb, lb);
        }
    }
}

// ---------------------------------------------------------------------------
// Kernel 4: merge chunk partials. One wave per (bh,u), lane = d.
// ---------------------------------------------------------------------------
__global__ __launch_bounds__(256) void merge_kernel(
        const float2* __restrict__ pml, const float* __restrict__ po,
        float* __restrict__ out) {
    int wid  = blockIdx.x * 4 + (threadIdx.x >> 6);
    int lane = threadIdx.x & 63;
    int u  = wid % NT;
    int bh = wid / NT;
    int h = bh & (HH - 1), b = bh >> 3;
    int base = (bh * NT + u) * NCH;

    float m = -INFINITY;
    #pragma unroll
    for (int cc = 0; cc < NCH; ++cc) m = fmaxf(m, pml[base + cc].x);
    float lsum = 0.0f, o = 0.0f;
    #pragma unroll
    for (int cc = 0; cc < NCH; ++cc) {
        float2 ml = pml[base + cc];
        float sc = __expf(ml.x - m);
        lsum += ml.y * sc;
        o    += po[(size_t)(base + cc) * DD + lane] * sc;
    }
    out[(((size_t)b * NT + u) * HH + h) * DD + lane] = o / lsum;
}

extern "C" void kernel_launch(void* const* d_in, const int* in_sizes, int n_in,
                              void* d_out, int out_size, void* d_ws, size_t ws_size,
                              hipStream_t stream) {
    const float* Q   = (const float*)d_in[0];
    const float* K   = (const float*)d_in[1];
    const float* V   = (const float*)d_in[2];
    const int*   idx = (const int*)d_in[3];
    float* out = (float*)d_out;

    char* ws = (char*)d_ws;
    float*  M    = (float*)ws;                        ws += (size_t)BB * HH * LL * sizeof(float);
    int*    topi = (int*)ws;                          ws += (size_t)BB * HH * NT * sizeof(int);
    float2* pml  = (float2*)ws;                       ws += (size_t)BB * HH * NT * NCH * sizeof(float2);
    float*  po   = (float*)ws;                        // 2.62 MB

    hipLaunchKernelGGL(compute_m_kernel, dim3(BB * LL), dim3(256), 0, stream,
                       Q, K, idx, M);
    hipLaunchKernelGGL(topk_kernel, dim3(BB * HH), dim3(256), 0, stream, M, topi);
    hipLaunchKernelGGL(attn_kernel, dim3(2 * BB * HH * NCH), dim3(256), 0, stream,
                       Q, K, V, topi, pml, po);
    hipLaunchKernelGGL(merge_kernel, dim3(BB * HH * NT / 4), dim3(256), 0, stream,
                       pml, po, out);
}